// Round 1
// baseline (10111.868 us; speedup 1.0000x reference)
//
#include <hip/hip_runtime.h>
#include <stdint.h>

typedef unsigned short u16;
typedef unsigned int   u32;
typedef __attribute__((ext_vector_type(8))) short s16x8;
typedef __attribute__((ext_vector_type(4))) float f32x4;

#define T_LEN 256

__device__ __forceinline__ u16 f2bf(float f){
  u32 u = __float_as_uint(f);
  u32 r = u + 0x7fffu + ((u >> 16) & 1u);
  return (u16)(r >> 16);
}
__device__ __forceinline__ float sigm(float x){ return 1.f/(1.f + __expf(-x)); }
__device__ __forceinline__ float tanh_f(float x){ return 2.f*sigm(2.f*x) - 1.f; }

// ---------------------------------------------------------------------------
// k_fuse: Wf0 = Wp@K0  [128,2048] (K=1024); Wf2 = Ws@K2 [128,2048] (K=512)
// ---------------------------------------------------------------------------
__global__ void k_fuse(const float* __restrict__ Wp, const float* __restrict__ K0,
                       const float* __restrict__ Ws, const float* __restrict__ K2,
                       float* __restrict__ Wf0, float* __restrict__ Wf2)
{
  const int c  = blockIdx.x*256 + threadIdx.x;   // 0..2047
  const int by = blockIdx.y;                     // 0..31
  float acc[8] = {0,0,0,0,0,0,0,0};
  if (by < 16){
    const int r0 = by*8;
    for (int d = 0; d < 1024; ++d){
      float kv = K0[(size_t)d*2048 + c];
      #pragma unroll
      for (int ii = 0; ii < 8; ++ii) acc[ii] = fmaf(Wp[(size_t)(r0+ii)*1024 + d], kv, acc[ii]);
    }
    #pragma unroll
    for (int ii = 0; ii < 8; ++ii) Wf0[(size_t)(r0+ii)*2048 + c] = acc[ii];
  } else {
    const int r0 = (by-16)*8;
    for (int u = 0; u < 512; ++u){
      float kv = K2[(size_t)u*2048 + c];
      #pragma unroll
      for (int ii = 0; ii < 8; ++ii) acc[ii] = fmaf(Ws[(size_t)(r0+ii)*512 + u], kv, acc[ii]);
    }
    #pragma unroll
    for (int ii = 0; ii < 8; ++ii) Wf2[(size_t)(r0+ii)*2048 + c] = acc[ii];
  }
}

// ---------------------------------------------------------------------------
// k_bias: gb0 = bp@K0 + b0 ; gb2 = bs@K2 + b2   (each [2048])
// ---------------------------------------------------------------------------
__global__ void k_bias(const float* __restrict__ bp, const float* __restrict__ K0,
                       const float* __restrict__ b0, const float* __restrict__ bs,
                       const float* __restrict__ K2, const float* __restrict__ b2,
                       float* __restrict__ gb0, float* __restrict__ gb2)
{
  const int bx = blockIdx.x;
  if (bx < 8){
    int c = bx*256 + threadIdx.x;
    float a = b0[c];
    for (int d = 0; d < 1024; ++d) a = fmaf(bp[d], K0[(size_t)d*2048 + c], a);
    gb0[c] = a;
  } else {
    int c = (bx-8)*256 + threadIdx.x;
    float a = b2[c];
    for (int u = 0; u < 512; ++u) a = fmaf(bs[u], K2[(size_t)u*2048 + c], a);
    gb2[c] = a;
  }
}

// ---------------------------------------------------------------------------
// k_zero: zero h ring buffers (3 layers x 4 slots x 64KB), flags = -1
// ---------------------------------------------------------------------------
__global__ void k_zero(u32* __restrict__ hbz, int* __restrict__ flags)
{
  int idx = blockIdx.x*256 + threadIdx.x;       // grid 768*256 = 196608 = hb u32 count
  if (idx < 196608) hbz[idx] = 0u;
  if (blockIdx.x == 0 && threadIdx.x < 192) flags[threadIdx.x] = -1;
}

// ---------------------------------------------------------------------------
// packing index helpers
// MFMA 16x16x32 bf16 frag conventions used everywhere:
//   A: lane holds A[m=lane&15][k=(lane>>4)*8+e]  (8 contiguous bf16 = 16B)
//   B: lane holds B[k=(lane>>4)*8+e][n=lane&15]
//   C/D: lane reg r holds D[row=(lane>>4)*4+r][col=lane&15]   (m89-verified)
// Buffers store tiles as [tile][k32][lane][8] so a wave load is 1KB contiguous.
// ---------------------------------------------------------------------------
__device__ __forceinline__ size_t gidx(int k, int c, int K32c){
  // gate-interleaved per-WG layout: WG j owns units j*8..j*8+7, local col lc = gate*8+uu
  int gate = c >> 9, u = c & 511;
  int jj = u >> 3, uu = u & 7;
  int lc = gate*8 + uu;
  return ((size_t)(jj*2 + (lc>>4))*K32c + (k>>5))*512
         + (size_t)((((k>>3)&3)*16 + (lc&15))*8) + (size_t)(k&7);
}
__device__ __forceinline__ size_t fidx(int k, int c){
  return ((size_t)(c>>4)*16 + (k>>5))*512
         + (size_t)((((k>>3)&3)*16 + (c&15))*8) + (size_t)(k&7);
}

// ---------------------------------------------------------------------------
// k_pack: bf16-pack all wavefront weights ([R0;Wf0], [R1;K1], [R2;K2;Wf2]),
// epilogue weights (W1,W2), and z into A-frag layout (zp).
// ---------------------------------------------------------------------------
__global__ void k_pack(const float* __restrict__ R0, const float* __restrict__ Wf0,
                       const float* __restrict__ R1, const float* __restrict__ K1,
                       const float* __restrict__ R2, const float* __restrict__ K2,
                       const float* __restrict__ Wf2, const float* __restrict__ W1,
                       const float* __restrict__ W2, const float* __restrict__ z,
                       u16* __restrict__ wgt0, u16* __restrict__ wgt1, u16* __restrict__ wgt2,
                       u16* __restrict__ w1p,  u16* __restrict__ w2p,  u16* __restrict__ zp)
{
  const long NT = 8159232;
  for (long i = (long)blockIdx.x*256 + threadIdx.x; i < NT; i += (long)gridDim.x*256){
    if (i < 1310720){                                   // layer0: K=640
      int k = (int)(i >> 11), c = (int)(i & 2047);
      float v = (k < 512) ? R0[(size_t)k*2048 + c] : Wf0[(size_t)(k-512)*2048 + c];
      wgt0[gidx(k, c, 20)] = f2bf(v);
    } else if (i < 3407872){                            // layer1: K=1024
      long i2 = i - 1310720; int k = (int)(i2 >> 11), c = (int)(i2 & 2047);
      float v = (k < 512) ? R1[(size_t)k*2048 + c] : K1[(size_t)(k-512)*2048 + c];
      wgt1[gidx(k, c, 32)] = f2bf(v);
    } else if (i < 5767168){                            // layer2: K=1152
      long i2 = i - 3407872; int k = (int)(i2 >> 11), c = (int)(i2 & 2047);
      float v = (k < 512)  ? R2[(size_t)k*2048 + c]
              : (k < 1024) ? K2[(size_t)(k-512)*2048 + c]
                           : Wf2[(size_t)(k-1024)*2048 + c];
      wgt2[gidx(k, c, 36)] = f2bf(v);
    } else if (i < 6029312){                            // W1 [512,512]
      long i2 = i - 5767168; int k = (int)(i2 >> 9), c = (int)(i2 & 511);
      w1p[fidx(k, c)] = f2bf(W1[(size_t)k*512 + c]);
    } else if (i < 6062080){                            // W2 [512,64]
      long i2 = i - 6029312; int k = (int)(i2 >> 6), c = (int)(i2 & 63);
      w2p[fidx(k, c)] = f2bf(W2[(size_t)k*64 + c]);
    } else {                                            // z -> A-frag layout per t
      long i2 = i - 6062080;
      int bb = (int)(i2 >> 15), rem = (int)(i2 & 32767);
      int tt = rem >> 7, k = rem & 127;
      zp[(((size_t)tt*4 + (bb>>4))*4 + (k>>5))*512
         + (size_t)((((k>>3)&3)*16 + (bb&15))*8) + (size_t)(k&7)] = f2bf(z[i2]);
    }
  }
}

// ---------------------------------------------------------------------------
// k_wave: persistent 3-layer LSTM wavefront. 192 blocks (layer = bid>>6,
// WG j = bid&63 owns hidden units j*8..j*8+7 = 32 gate columns).
// Per global step s, layer L computes t=s-L:
//   zg = [h_prev_L ; h_below ; (z_t)] @ [R ; K ; Wfuse] + bias
// h ring buffer: 4 slots, frag layout, bf16. Flag-based sync (no grid barrier).
// ---------------------------------------------------------------------------
#define GEMM_SEG(BASE, CNT, LDSOFF, K32C)                                          \
  { const u16* bptr_ = (BASE);                                                     \
    _Pragma("unroll")                                                              \
    for (int kk = 0; kk < (CNT); ++kk){                                            \
      s16x8 av  = *(const s16x8*)(bptr_ + (size_t)kk*512);                         \
      s16x8 bv0 = *(const s16x8*)&wsm[(((LDSOFF)+kk)*512) + lane*8];               \
      s16x8 bv1 = *(const s16x8*)&wsm[(((K32C)+(LDSOFF)+kk)*512) + lane*8];        \
      acc0 = __builtin_amdgcn_mfma_f32_16x16x32_bf16(av, bv0, acc0, 0, 0, 0);      \
      acc1 = __builtin_amdgcn_mfma_f32_16x16x32_bf16(av, bv1, acc1, 0, 0, 0);      \
    } }

__global__ __launch_bounds__(256) void k_wave(
    const u16* __restrict__ wgt0, const u16* __restrict__ wgt1, const u16* __restrict__ wgt2,
    const u16* __restrict__ zp, u16* __restrict__ hb, float* __restrict__ hout,
    int* flags, const float* __restrict__ gb0, const float* __restrict__ b1g,
    const float* __restrict__ gb2)
{
  __shared__ __align__(16) u16 wsm[2*36*512];      // 72KB weight slice
  __shared__ float zg[64][33];                     // padded: gate reads conflict-free
  const int tid = threadIdx.x;
  const int bid = blockIdx.x;
  const int L   = bid >> 6;
  const int j   = bid & 63;
  const int K32r = (L==0) ? 20 : ((L==1) ? 32 : 36);

  // load my weight slice into LDS (resident for all 256 steps)
  { const u16* wsrc = (L==0) ? wgt0 + (size_t)j*20480
                    : (L==1) ? wgt1 + (size_t)j*32768
                             : wgt2 + (size_t)j*36864;
    const uint4* s4 = (const uint4*)wsrc; uint4* d4 = (uint4*)wsm;
    const int n4 = K32r*128;
    for (int i = tid; i < n4; i += 256) d4[i] = s4[i]; }

  const int b    = tid & 63;        // batch row (gate stage)
  const int q    = tid >> 6;        // wave id / unit subgroup
  const int w    = q;               // m-tile for MFMA stage
  const int lane = tid & 63;

  float bias[2][4];
  { const float* bsrc = (L==0) ? gb0 : (L==1) ? b1g : gb2;
    #pragma unroll
    for (int ci = 0; ci < 2; ++ci){
      int ucol = j*8 + q + ci*4;
      #pragma unroll
      for (int g = 0; g < 4; ++g) bias[ci][g] = bsrc[g*512 + ucol];
    } }
  float cst0 = 0.f, cst1 = 0.f;     // fp32 cell state, register-resident

  // flag protocol: consumer needs layers <=L done >= s-1; producer-credit needs
  // layer L+1 done >= s-3 (4-slot ring). Others irrelevant.
  bool fcare = false; int foff = 0;
  if (tid < 192){
    int rel = (tid >> 6) - L;
    fcare = (rel >= -1) && (rel <= 1);
    foff  = (rel <= 0) ? -1 : -3;
  }

  const int   laneW  = ((j & 3) << 4) | (b & 15);
  const size_t hoffw = ((((size_t)(b >> 4))*16 + (j >> 2))*64 + laneW)*8;

  __syncthreads();

  for (int s = 0; s < T_LEN + 2; ++s){
    // ---- wait on flags (relaxed agent loads; bailout guard instead of hang)
    int ok, guard = 0;
    do {
      ok = 1;
      if (fcare){
        int v = __hip_atomic_load(&flags[tid], __ATOMIC_RELAXED, __HIP_MEMORY_SCOPE_AGENT);
        ok = (v >= s + foff);
      }
    } while (!__syncthreads_and(ok) && ++guard < (1<<20));
    __threadfence();   // acquire: invalidate caches so h reads are fresh

    const int t = s - L;
    if (t >= 0 && t < T_LEN){
      const int slp = (s + 3) & 3;  // previous slot
      f32x4 acc0 = {0.f,0.f,0.f,0.f};
      f32x4 acc1 = {0.f,0.f,0.f,0.f};
      const size_t wl8 = (size_t)w*8192 + (size_t)lane*8;
      const u16* h0p = hb + (size_t)(0*4 + slp)*32768 + wl8;
      const u16* h1p = hb + (size_t)(1*4 + slp)*32768 + wl8;
      const u16* h2p = hb + (size_t)(2*4 + slp)*32768 + wl8;
      const u16* zpt = zp + (size_t)t*8192 + (size_t)w*2048 + (size_t)lane*8;

      if (L == 0){
        GEMM_SEG(h0p, 16, 0, 20)
        GEMM_SEG(zpt,  4, 16, 20)
      } else if (L == 1){
        GEMM_SEG(h1p, 16, 0, 32)
        GEMM_SEG(h0p, 16, 16, 32)
      } else {
        GEMM_SEG(h2p, 16, 0, 36)
        GEMM_SEG(h1p, 16, 16, 36)
        GEMM_SEG(zpt,  4, 32, 36)
      }
      #pragma unroll
      for (int r = 0; r < 4; ++r){
        int row = (w << 4) + ((lane >> 4) << 2) + r;   // C/D: row=(lane>>4)*4+r
        zg[row][lane & 15]        = acc0[r];
        zg[row][16 + (lane & 15)] = acc1[r];
      }
      __syncthreads();

      // ---- gates (thread handles (b, units q and q+4)); c stays fp32 in regs
      const int sl = s & 3;
      u16* hdst = hb + (size_t)(L*4 + sl)*32768;
      float hv0, hv1;
      {
        int uu = q;
        float zi = zg[b][uu]      + bias[0][0];
        float zf = zg[b][8 + uu]  + bias[0][1];
        float zc = zg[b][16 + uu] + bias[0][2];
        float zo = zg[b][24 + uu] + bias[0][3];
        float cc = sigm(zf)*cst0 + sigm(zi)*tanh_f(zc);
        cst0 = cc; hv0 = sigm(zo)*tanh_f(cc);
        hdst[hoffw + uu] = f2bf(hv0);
      }
      {
        int uu = q + 4;
        float zi = zg[b][uu]      + bias[1][0];
        float zf = zg[b][8 + uu]  + bias[1][1];
        float zc = zg[b][16 + uu] + bias[1][2];
        float zo = zg[b][24 + uu] + bias[1][3];
        float cc = sigm(zf)*cst1 + sigm(zi)*tanh_f(zc);
        cst1 = cc; hv1 = sigm(zo)*tanh_f(cc);
        hdst[hoffw + uu] = f2bf(hv1);
      }
      if (L == 2){
        size_t o = ((size_t)t*64 + b)*512 + j*8 + q;
        hout[o]     = hv0;
        hout[o + 4] = hv1;
      }
    }
    // ---- publish step s
    __threadfence();   // release: drain + write back
    __syncthreads();
    if (tid == 0) __hip_atomic_store(&flags[bid], s, __ATOMIC_RELAXED, __HIP_MEMORY_SCOPE_AGENT);
  }
}

// ---------------------------------------------------------------------------
// k_ep: per-t block (256 blocks): LayerNorm -> W1+relu -> W2+tanh -> out
// ---------------------------------------------------------------------------
__global__ __launch_bounds__(256) void k_ep(
    const float* __restrict__ hout, const float* __restrict__ gam, const float* __restrict__ bet,
    const u16* __restrict__ w1p, const u16* __restrict__ w2p,
    const float* __restrict__ b1d, const float* __restrict__ b2d, float* __restrict__ out)
{
  __shared__ __align__(16) u16 xf[32768];   // LN(x) bf16, frag layout [mt][k32][lane][8]
  __shared__ __align__(16) u16 yf[32768];   // relu(xW1+b) bf16, frag layout
  __shared__ float redS[64][8];
  __shared__ float muS[64], rsS[64];
  const int t = blockIdx.x, tid = threadIdx.x;
  const int r = tid >> 2, qq = tid & 3;

  const float4* x4 = (const float4*)(hout + ((size_t)t*64 + r)*512 + qq*128);
  float sum = 0.f, sq = 0.f;
  #pragma unroll 8
  for (int i = 0; i < 32; ++i){
    float4 v = x4[i];
    sum += v.x + v.y + v.z + v.w;
    sq  += v.x*v.x + v.y*v.y + v.z*v.z + v.w*v.w;
  }
  redS[r][qq] = sum; redS[r][4+qq] = sq;
  __syncthreads();
  if (qq == 0){
    float s1 = redS[r][0]+redS[r][1]+redS[r][2]+redS[r][3];
    float s2 = redS[r][4]+redS[r][5]+redS[r][6]+redS[r][7];
    float m  = s1 * (1.f/512.f);
    float var = s2 * (1.f/512.f) - m*m;
    muS[r] = m; rsS[r] = rsqrtf(var + 1e-3f);
  }
  __syncthreads();
  { const float m = muS[r], rstd = rsS[r];
    const int mt = r >> 4, rl = r & 15;
    for (int i = 0; i < 32; ++i){
      float4 v = x4[i];
      int k0 = qq*128 + i*4;
      float vv[4] = {v.x, v.y, v.z, v.w};
      #pragma unroll
      for (int e = 0; e < 4; ++e){
        int k = k0 + e;
        float xn = (vv[e] - m)*rstd*gam[k] + bet[k];
        xf[((mt*16 + (k>>5))*64 + ((k>>3)&3)*16 + rl)*8 + (k&7)] = f2bf(xn);
      }
    } }
  __syncthreads();

  const int w = tid >> 6, lane = tid & 63;
  // GEMM1: [64,512] @ W1[512,512], wave owns 8 n16-tiles
  f32x4 acc[4][8];
  f32x4 vz = {0.f,0.f,0.f,0.f};
  #pragma unroll
  for (int a = 0; a < 4; ++a)
    #pragma unroll
    for (int n = 0; n < 8; ++n) acc[a][n] = vz;
  for (int k32 = 0; k32 < 16; ++k32){
    s16x8 av[4];
    #pragma unroll
    for (int mt = 0; mt < 4; ++mt) av[mt] = *(const s16x8*)&xf[((mt*16 + k32)*64 + lane)*8];
    #pragma unroll
    for (int nn = 0; nn < 8; ++nn){
      const int n16 = w*8 + nn;
      s16x8 bv = *(const s16x8*)&w1p[((size_t)(n16*16 + k32)*64 + lane)*8];
      #pragma unroll
      for (int mt = 0; mt < 4; ++mt)
        acc[mt][nn] = __builtin_amdgcn_mfma_f32_16x16x32_bf16(av[mt], bv, acc[mt][nn], 0,0,0);
    }
  }
  #pragma unroll
  for (int nn = 0; nn < 8; ++nn){
    int col = (w*8 + nn)*16 + (lane & 15);
    float bv = b1d[col];
    #pragma unroll
    for (int mt = 0; mt < 4; ++mt){
      #pragma unroll
      for (int rr = 0; rr < 4; ++rr){
        int row = mt*16 + ((lane >> 4) << 2) + rr;
        float v = acc[mt][nn][rr] + bv;
        v = fmaxf(v, 0.f);
        yf[((mt*16 + (col>>5))*64 + ((col>>3)&3)*16 + (row&15))*8 + (col&7)] = f2bf(v);
      } } }
  __syncthreads();

  // GEMM2: [64,512] @ W2[512,64], wave owns n16-tile w
  f32x4 acc2[4];
  #pragma unroll
  for (int mt = 0; mt < 4; ++mt) acc2[mt] = vz;
  for (int k32 = 0; k32 < 16; ++k32){
    s16x8 bv = *(const s16x8*)&w2p[((size_t)(w*16 + k32)*64 + lane)*8];
    #pragma unroll
    for (int mt = 0; mt < 4; ++mt){
      s16x8 av = *(const s16x8*)&yf[((mt*16 + k32)*64 + lane)*8];
      acc2[mt] = __builtin_amdgcn_mfma_f32_16x16x32_bf16(av, bv, acc2[mt], 0,0,0);
    } }
  const int f = w*16 + (lane & 15);
  const float bf_ = b2d[f];
  #pragma unroll
  for (int mt = 0; mt < 4; ++mt)
    #pragma unroll
    for (int rr = 0; rr < 4; ++rr){
      int row = mt*16 + ((lane >> 4) << 2) + rr;             // batch index
      out[((size_t)row*T_LEN + t)*64 + f] = tanh_f(acc2[mt][rr] + bf_);
    }
}

// ---------------------------------------------------------------------------
extern "C" void kernel_launch(void* const* d_in, const int* in_sizes, int n_in,
                              void* d_out, int out_size, void* d_ws, size_t ws_size,
                              hipStream_t stream)
{
  const float* z    = (const float*)d_in[0];
  const float* Wp   = (const float*)d_in[1];
  const float* bp   = (const float*)d_in[2];
  const float* Ws   = (const float*)d_in[3];
  const float* bs   = (const float*)d_in[4];
  const float* K0   = (const float*)d_in[5];
  const float* R0   = (const float*)d_in[6];
  const float* b0   = (const float*)d_in[7];
  const float* K1   = (const float*)d_in[8];
  const float* R1   = (const float*)d_in[9];
  const float* b1   = (const float*)d_in[10];
  const float* K2   = (const float*)d_in[11];
  const float* R2   = (const float*)d_in[12];
  const float* b2   = (const float*)d_in[13];
  const float* gam  = (const float*)d_in[14];
  const float* bet  = (const float*)d_in[15];
  const float* W1   = (const float*)d_in[16];
  const float* b1d  = (const float*)d_in[17];
  const float* W2   = (const float*)d_in[18];
  const float* b2d  = (const float*)d_in[19];
  float* out = (float*)d_out;
  (void)in_sizes; (void)n_in; (void)out_size; (void)ws_size;

  char* base = (char*)d_ws;
  size_t off = 0;
  auto carve = [&](size_t bytes)->char* {
    char* p = base + off;
    off = (off + bytes + 255) & ~(size_t)255;
    return p;
  };
  u16*   wgt0 = (u16*)  carve((size_t)64*20480*2);   // [R0;Wf0] packed
  u16*   wgt1 = (u16*)  carve((size_t)64*32768*2);   // [R1;K1]
  u16*   wgt2 = (u16*)  carve((size_t)64*36864*2);   // [R2;K2;Wf2]
  u16*   w1p  = (u16*)  carve((size_t)262144*2);
  u16*   w2p  = (u16*)  carve((size_t)32768*2);
  u16*   zp   = (u16*)  carve((size_t)2097152*2);    // z in A-frag layout
  float* Wf0  = (float*)carve((size_t)262144*4);
  float* Wf2  = (float*)carve((size_t)262144*4);
  float* gb0  = (float*)carve((size_t)2048*4);
  float* gb2  = (float*)carve((size_t)2048*4);
  u16*   hb   = (u16*)  carve((size_t)393216*2);     // 3 layers x 4 slots x 64KB
  float* hout = (float*)carve((size_t)8388608*4);    // lstm2 output [t][b][512]
  int*   flags= (int*)  carve((size_t)4096);

  k_fuse<<<dim3(8,32), dim3(256), 0, stream>>>(Wp, K0, Ws, K2, Wf0, Wf2);
  k_bias<<<dim3(16),   dim3(256), 0, stream>>>(bp, K0, b0, bs, K2, b2, gb0, gb2);
  k_zero<<<dim3(768),  dim3(256), 0, stream>>>((u32*)hb, flags);
  k_pack<<<dim3(4096), dim3(256), 0, stream>>>(R0, Wf0, R1, K1, R2, K2, Wf2, W1, W2, z,
                                               wgt0, wgt1, wgt2, w1p, w2p, zp);
  k_wave<<<dim3(192),  dim3(256), 0, stream>>>(wgt0, wgt1, wgt2, zp, hb, hout, flags,
                                               gb0, b1, gb2);
  k_ep<<<dim3(256),    dim3(256), 0, stream>>>(hout, gam, bet, w1p, w2p, b1d, b2d, out);
}

// Round 2
// 2745.542 us; speedup vs baseline: 3.6830x; 3.6830x over previous
//
#include <hip/hip_runtime.h>
#include <stdint.h>

typedef unsigned short u16;
typedef unsigned int   u32;
typedef unsigned long long u64;
typedef __attribute__((ext_vector_type(8))) short s16x8;
typedef __attribute__((ext_vector_type(4))) float f32x4;

#define T_LEN 256

__device__ __forceinline__ u16 f2bf(float f){
  u32 u = __float_as_uint(f);
  u32 r = u + 0x7fffu + ((u >> 16) & 1u);
  return (u16)(r >> 16);
}
__device__ __forceinline__ float sigm(float x){ return 1.f/(1.f + __expf(-x)); }
__device__ __forceinline__ float tanh_f(float x){ return 2.f*sigm(2.f*x) - 1.f; }

// agent-coherent (LLC) 16B load as two 8B relaxed atomics: global_load_dwordx2 sc1,
// bypasses L1/L2 so cross-XCD h reads are fresh WITHOUT any buffer_inv.
__device__ __forceinline__ s16x8 ldh(const u16* p){
  u64 lo = __hip_atomic_load((const u64*)p,       __ATOMIC_RELAXED, __HIP_MEMORY_SCOPE_AGENT);
  u64 hi = __hip_atomic_load((const u64*)(p + 4), __ATOMIC_RELAXED, __HIP_MEMORY_SCOPE_AGENT);
  union { u64 q[2]; s16x8 v; } u;
  u.q[0] = lo; u.q[1] = hi;
  return u.v;
}

// ---------------------------------------------------------------------------
// k_fuse: Wf0 = Wp@K0  [128,2048] (K=1024); Wf2 = Ws@K2 [128,2048] (K=512)
// ---------------------------------------------------------------------------
__global__ void k_fuse(const float* __restrict__ Wp, const float* __restrict__ K0,
                       const float* __restrict__ Ws, const float* __restrict__ K2,
                       float* __restrict__ Wf0, float* __restrict__ Wf2)
{
  const int c  = blockIdx.x*256 + threadIdx.x;   // 0..2047
  const int by = blockIdx.y;                     // 0..31
  float acc[8] = {0,0,0,0,0,0,0,0};
  if (by < 16){
    const int r0 = by*8;
    for (int d = 0; d < 1024; ++d){
      float kv = K0[(size_t)d*2048 + c];
      #pragma unroll
      for (int ii = 0; ii < 8; ++ii) acc[ii] = fmaf(Wp[(size_t)(r0+ii)*1024 + d], kv, acc[ii]);
    }
    #pragma unroll
    for (int ii = 0; ii < 8; ++ii) Wf0[(size_t)(r0+ii)*2048 + c] = acc[ii];
  } else {
    const int r0 = (by-16)*8;
    for (int u = 0; u < 512; ++u){
      float kv = K2[(size_t)u*2048 + c];
      #pragma unroll
      for (int ii = 0; ii < 8; ++ii) acc[ii] = fmaf(Ws[(size_t)(r0+ii)*512 + u], kv, acc[ii]);
    }
    #pragma unroll
    for (int ii = 0; ii < 8; ++ii) Wf2[(size_t)(r0+ii)*2048 + c] = acc[ii];
  }
}

// ---------------------------------------------------------------------------
// k_bias: gb0 = bp@K0 + b0 ; gb2 = bs@K2 + b2   (each [2048])
// ---------------------------------------------------------------------------
__global__ void k_bias(const float* __restrict__ bp, const float* __restrict__ K0,
                       const float* __restrict__ b0, const float* __restrict__ bs,
                       const float* __restrict__ K2, const float* __restrict__ b2,
                       float* __restrict__ gb0, float* __restrict__ gb2)
{
  const int bx = blockIdx.x;
  if (bx < 8){
    int c = bx*256 + threadIdx.x;
    float a = b0[c];
    for (int d = 0; d < 1024; ++d) a = fmaf(bp[d], K0[(size_t)d*2048 + c], a);
    gb0[c] = a;
  } else {
    int c = (bx-8)*256 + threadIdx.x;
    float a = b2[c];
    for (int u = 0; u < 512; ++u) a = fmaf(bs[u], K2[(size_t)u*2048 + c], a);
    gb2[c] = a;
  }
}

// ---------------------------------------------------------------------------
// k_zero: zero h ring buffers (3 layers x 4 slots x 64KB), flags = -1
// ---------------------------------------------------------------------------
__global__ void k_zero(u32* __restrict__ hbz, int* __restrict__ flags)
{
  int idx = blockIdx.x*256 + threadIdx.x;       // grid 768*256 = 196608 = hb u32 count
  if (idx < 196608) hbz[idx] = 0u;
  if (blockIdx.x == 0 && threadIdx.x < 192) flags[threadIdx.x] = -1;
}

// ---------------------------------------------------------------------------
// packing index helpers
// MFMA 16x16x32 bf16 frag conventions used everywhere:
//   A: lane holds A[m=lane&15][k=(lane>>4)*8+e]  (8 contiguous bf16 = 16B)
//   B: lane holds B[k=(lane>>4)*8+e][n=lane&15]
//   C/D: lane reg r holds D[row=(lane>>4)*4+r][col=lane&15]   (m89-verified)
// Buffers store tiles as [tile][k32][lane][8] so a wave load is 1KB contiguous.
// ---------------------------------------------------------------------------
__device__ __forceinline__ size_t gidx(int k, int c, int K32c){
  // gate-interleaved per-WG layout: WG j owns units j*8..j*8+7, local col lc = gate*8+uu
  int gate = c >> 9, u = c & 511;
  int jj = u >> 3, uu = u & 7;
  int lc = gate*8 + uu;
  return ((size_t)(jj*2 + (lc>>4))*K32c + (k>>5))*512
         + (size_t)((((k>>3)&3)*16 + (lc&15))*8) + (size_t)(k&7);
}
__device__ __forceinline__ size_t fidx(int k, int c){
  return ((size_t)(c>>4)*16 + (k>>5))*512
         + (size_t)((((k>>3)&3)*16 + (c&15))*8) + (size_t)(k&7);
}

// ---------------------------------------------------------------------------
// k_pack: bf16-pack all wavefront weights ([R0;Wf0], [R1;K1], [R2;K2;Wf2]),
// epilogue weights (W1,W2), and z into A-frag layout (zp).
// ---------------------------------------------------------------------------
__global__ void k_pack(const float* __restrict__ R0, const float* __restrict__ Wf0,
                       const float* __restrict__ R1, const float* __restrict__ K1,
                       const float* __restrict__ R2, const float* __restrict__ K2,
                       const float* __restrict__ Wf2, const float* __restrict__ W1,
                       const float* __restrict__ W2, const float* __restrict__ z,
                       u16* __restrict__ wgt0, u16* __restrict__ wgt1, u16* __restrict__ wgt2,
                       u16* __restrict__ w1p,  u16* __restrict__ w2p,  u16* __restrict__ zp)
{
  const long NT = 8159232;
  for (long i = (long)blockIdx.x*256 + threadIdx.x; i < NT; i += (long)gridDim.x*256){
    if (i < 1310720){                                   // layer0: K=640
      int k = (int)(i >> 11), c = (int)(i & 2047);
      float v = (k < 512) ? R0[(size_t)k*2048 + c] : Wf0[(size_t)(k-512)*2048 + c];
      wgt0[gidx(k, c, 20)] = f2bf(v);
    } else if (i < 3407872){                            // layer1: K=1024
      long i2 = i - 1310720; int k = (int)(i2 >> 11), c = (int)(i2 & 2047);
      float v = (k < 512) ? R1[(size_t)k*2048 + c] : K1[(size_t)(k-512)*2048 + c];
      wgt1[gidx(k, c, 32)] = f2bf(v);
    } else if (i < 5767168){                            // layer2: K=1152
      long i2 = i - 3407872; int k = (int)(i2 >> 11), c = (int)(i2 & 2047);
      float v = (k < 512)  ? R2[(size_t)k*2048 + c]
              : (k < 1024) ? K2[(size_t)(k-512)*2048 + c]
                           : Wf2[(size_t)(k-1024)*2048 + c];
      wgt2[gidx(k, c, 36)] = f2bf(v);
    } else if (i < 6029312){                            // W1 [512,512]
      long i2 = i - 5767168; int k = (int)(i2 >> 9), c = (int)(i2 & 511);
      w1p[fidx(k, c)] = f2bf(W1[(size_t)k*512 + c]);
    } else if (i < 6062080){                            // W2 [512,64]
      long i2 = i - 6029312; int k = (int)(i2 >> 6), c = (int)(i2 & 63);
      w2p[fidx(k, c)] = f2bf(W2[(size_t)k*64 + c]);
    } else {                                            // z -> A-frag layout per t
      long i2 = i - 6062080;
      int bb = (int)(i2 >> 15), rem = (int)(i2 & 32767);
      int tt = rem >> 7, k = rem & 127;
      zp[(((size_t)tt*4 + (bb>>4))*4 + (k>>5))*512
         + (size_t)((((k>>3)&3)*16 + (bb&15))*8) + (size_t)(k&7)] = f2bf(z[i2]);
    }
  }
}

// ---------------------------------------------------------------------------
// k_wave: persistent 3-layer LSTM wavefront. 192 blocks (layer = bid>>6,
// WG j = bid&63 owns hidden units j*8..j*8+7 = 32 gate columns).
// Per global step s, layer L computes t=s-L.
// Sync: NO __threadfence (agent fences = full L2 wb/inv on gfx950 = 38us/step
// in R1). Instead all cross-block data (h ring, flags) moves via relaxed
// agent-scope atomics (sc1: LLC-coherent, no cache maintenance). Producer
// ordering: __syncthreads drains vmcnt(0) before flag publish. Consumer
// ordering: flag-dependent branch + barrier.
// ---------------------------------------------------------------------------
#define GEMM_SEG_H(BASE, CNT, LDSOFF, K32C)                                        \
  { const u16* bptr_ = (BASE);                                                     \
    s16x8 areg[CNT];                                                               \
    _Pragma("unroll")                                                              \
    for (int kk = 0; kk < (CNT); ++kk) areg[kk] = ldh(bptr_ + (size_t)kk*512);     \
    _Pragma("unroll")                                                              \
    for (int kk = 0; kk < (CNT); ++kk){                                            \
      s16x8 bv0 = *(const s16x8*)&wsm[(((LDSOFF)+kk)*512) + lane*8];               \
      s16x8 bv1 = *(const s16x8*)&wsm[(((K32C)+(LDSOFF)+kk)*512) + lane*8];        \
      acc0 = __builtin_amdgcn_mfma_f32_16x16x32_bf16(areg[kk], bv0, acc0, 0, 0, 0);\
      acc1 = __builtin_amdgcn_mfma_f32_16x16x32_bf16(areg[kk], bv1, acc1, 0, 0, 0);\
    } }

#define GEMM_SEG_Z(BASE, CNT, LDSOFF, K32C)                                        \
  { const u16* bptr_ = (BASE);                                                     \
    _Pragma("unroll")                                                              \
    for (int kk = 0; kk < (CNT); ++kk){                                            \
      s16x8 av  = *(const s16x8*)(bptr_ + (size_t)kk*512);                         \
      s16x8 bv0 = *(const s16x8*)&wsm[(((LDSOFF)+kk)*512) + lane*8];               \
      s16x8 bv1 = *(const s16x8*)&wsm[(((K32C)+(LDSOFF)+kk)*512) + lane*8];        \
      acc0 = __builtin_amdgcn_mfma_f32_16x16x32_bf16(av, bv0, acc0, 0, 0, 0);      \
      acc1 = __builtin_amdgcn_mfma_f32_16x16x32_bf16(av, bv1, acc1, 0, 0, 0);      \
    } }

__global__ __launch_bounds__(256) void k_wave(
    const u16* __restrict__ wgt0, const u16* __restrict__ wgt1, const u16* __restrict__ wgt2,
    const u16* __restrict__ zp, u16* __restrict__ hb, float* __restrict__ hout,
    int* flags, const float* __restrict__ gb0, const float* __restrict__ b1g,
    const float* __restrict__ gb2)
{
  __shared__ __align__(16) u16 wsm[2*36*512];      // 72KB weight slice
  __shared__ float zg[64][33];                     // padded: gate reads conflict-free
  const int tid = threadIdx.x;
  const int bid = blockIdx.x;
  const int L   = bid >> 6;
  const int j   = bid & 63;
  const int K32r = (L==0) ? 20 : ((L==1) ? 32 : 36);

  // load my weight slice into LDS (resident for all 256 steps)
  { const u16* wsrc = (L==0) ? wgt0 + (size_t)j*20480
                    : (L==1) ? wgt1 + (size_t)j*32768
                             : wgt2 + (size_t)j*36864;
    const uint4* s4 = (const uint4*)wsrc; uint4* d4 = (uint4*)wsm;
    const int n4 = K32r*128;
    for (int i = tid; i < n4; i += 256) d4[i] = s4[i]; }

  const int b    = tid & 63;        // batch row (gate stage)
  const int q    = tid >> 6;        // wave id; gate stage owns units 2q, 2q+1
  const int w    = q;               // m-tile for MFMA stage
  const int lane = tid & 63;

  float bias[2][4];
  { const float* bsrc = (L==0) ? gb0 : (L==1) ? b1g : gb2;
    #pragma unroll
    for (int ci = 0; ci < 2; ++ci){
      int ucol = j*8 + 2*q + ci;
      #pragma unroll
      for (int g = 0; g < 4; ++g) bias[ci][g] = bsrc[g*512 + ucol];
    } }
  float cst0 = 0.f, cst1 = 0.f;     // fp32 cell state, register-resident

  // flag protocol: consumer needs layers <=L done >= s-1; producer-credit needs
  // layer L+1 done >= s-3 (4-slot ring). Others irrelevant.
  bool fcare = false; int foff = 0;
  if (tid < 192){
    int rel = (tid >> 6) - L;
    fcare = (rel >= -1) && (rel <= 1);
    foff  = (rel <= 0) ? -1 : -3;
  }

  const int   laneW  = ((j & 3) << 4) | (b & 15);
  const size_t hoffw = ((((size_t)(b >> 4))*16 + (j >> 2))*64 + laneW)*8;

  __syncthreads();

  for (int s = 0; s < T_LEN + 2; ++s){
    // ---- wait on flags (relaxed agent loads straight from LLC; guard = bailout)
    if (fcare){
      const int target = s + foff;
      int guard = 0;
      while (__hip_atomic_load(&flags[tid], __ATOMIC_RELAXED, __HIP_MEMORY_SCOPE_AGENT) < target){
        __builtin_amdgcn_s_sleep(1);
        if (++guard > (1<<16)) break;
      }
    }
    __syncthreads();

    const int t = s - L;
    if (t >= 0 && t < T_LEN){
      const int slp = (s + 3) & 3;  // previous slot
      f32x4 acc0 = {0.f,0.f,0.f,0.f};
      f32x4 acc1 = {0.f,0.f,0.f,0.f};
      const size_t wl8 = (size_t)w*8192 + (size_t)lane*8;
      const u16* h0p = hb + (size_t)(0*4 + slp)*32768 + wl8;
      const u16* h1p = hb + (size_t)(1*4 + slp)*32768 + wl8;
      const u16* h2p = hb + (size_t)(2*4 + slp)*32768 + wl8;
      const u16* zpt = zp + (size_t)t*8192 + (size_t)w*2048 + (size_t)lane*8;

      if (L == 0){
        GEMM_SEG_H(h0p, 16, 0, 20)
        GEMM_SEG_Z(zpt,  4, 16, 20)
      } else if (L == 1){
        GEMM_SEG_H(h1p, 16, 0, 32)
        GEMM_SEG_H(h0p, 16, 16, 32)
      } else {
        GEMM_SEG_H(h2p, 16, 0, 36)
        GEMM_SEG_H(h1p, 16, 16, 36)
        GEMM_SEG_Z(zpt,  4, 32, 36)
      }
      #pragma unroll
      for (int r = 0; r < 4; ++r){
        int row = (w << 4) + ((lane >> 4) << 2) + r;   // C/D: row=(lane>>4)*4+r
        zg[row][lane & 15]        = acc0[r];
        zg[row][16 + (lane & 15)] = acc1[r];
      }
      __syncthreads();

      // ---- gates: thread handles (b, units 2q and 2q+1); c stays fp32 in regs
      const int sl = s & 3;
      u32* hdst32 = (u32*)(hb + (size_t)(L*4 + sl)*32768);
      float hv0, hv1;
      {
        int uu = 2*q;
        float zi = zg[b][uu]      + bias[0][0];
        float zf = zg[b][8 + uu]  + bias[0][1];
        float zc = zg[b][16 + uu] + bias[0][2];
        float zo = zg[b][24 + uu] + bias[0][3];
        float cc = sigm(zf)*cst0 + sigm(zi)*tanh_f(zc);
        cst0 = cc; hv0 = sigm(zo)*tanh_f(cc);
      }
      {
        int uu = 2*q + 1;
        float zi = zg[b][uu]      + bias[1][0];
        float zf = zg[b][8 + uu]  + bias[1][1];
        float zc = zg[b][16 + uu] + bias[1][2];
        float zo = zg[b][24 + uu] + bias[1][3];
        float cc = sigm(zf)*cst1 + sigm(zi)*tanh_f(zc);
        cst1 = cc; hv1 = sigm(zo)*tanh_f(cc);
      }
      // packed agent-scope store: write-through to LLC, visible to all XCDs
      u32 packed = (u32)f2bf(hv0) | ((u32)f2bf(hv1) << 16);
      __hip_atomic_store(&hdst32[(hoffw >> 1) + q], packed,
                         __ATOMIC_RELAXED, __HIP_MEMORY_SCOPE_AGENT);
      if (L == 2){
        size_t o = ((size_t)t*64 + b)*512 + j*8 + 2*q;
        hout[o]     = hv0;   // plain cached store; flushed at kernel end for k_ep
        hout[o + 1] = hv1;
      }
    }
    // ---- publish step s: __syncthreads drains vmcnt(0) (all h stores at LLC),
    // then one relaxed agent flag store. No cache maintenance anywhere.
    __syncthreads();
    if (tid == 0) __hip_atomic_store(&flags[bid], s, __ATOMIC_RELAXED, __HIP_MEMORY_SCOPE_AGENT);
  }
}

// ---------------------------------------------------------------------------
// k_ep: per-t block (256 blocks): LayerNorm -> W1+relu -> W2+tanh -> out
// ---------------------------------------------------------------------------
__global__ __launch_bounds__(256) void k_ep(
    const float* __restrict__ hout, const float* __restrict__ gam, const float* __restrict__ bet,
    const u16* __restrict__ w1p, const u16* __restrict__ w2p,
    const float* __restrict__ b1d, const float* __restrict__ b2d, float* __restrict__ out)
{
  __shared__ __align__(16) u16 xf[32768];   // LN(x) bf16, frag layout [mt][k32][lane][8]
  __shared__ __align__(16) u16 yf[32768];   // relu(xW1+b) bf16, frag layout
  __shared__ float redS[64][8];
  __shared__ float muS[64], rsS[64];
  const int t = blockIdx.x, tid = threadIdx.x;
  const int r = tid >> 2, qq = tid & 3;

  const float4* x4 = (const float4*)(hout + ((size_t)t*64 + r)*512 + qq*128);
  float sum = 0.f, sq = 0.f;
  #pragma unroll 8
  for (int i = 0; i < 32; ++i){
    float4 v = x4[i];
    sum += v.x + v.y + v.z + v.w;
    sq  += v.x*v.x + v.y*v.y + v.z*v.z + v.w*v.w;
  }
  redS[r][qq] = sum; redS[r][4+qq] = sq;
  __syncthreads();
  if (qq == 0){
    float s1 = redS[r][0]+redS[r][1]+redS[r][2]+redS[r][3];
    float s2 = redS[r][4]+redS[r][5]+redS[r][6]+redS[r][7];
    float m  = s1 * (1.f/512.f);
    float var = s2 * (1.f/512.f) - m*m;
    muS[r] = m; rsS[r] = rsqrtf(var + 1e-3f);
  }
  __syncthreads();
  { const float m = muS[r], rstd = rsS[r];
    const int mt = r >> 4, rl = r & 15;
    for (int i = 0; i < 32; ++i){
      float4 v = x4[i];
      int k0 = qq*128 + i*4;
      float vv[4] = {v.x, v.y, v.z, v.w};
      #pragma unroll
      for (int e = 0; e < 4; ++e){
        int k = k0 + e;
        float xn = (vv[e] - m)*rstd*gam[k] + bet[k];
        xf[((mt*16 + (k>>5))*64 + ((k>>3)&3)*16 + rl)*8 + (k&7)] = f2bf(xn);
      }
    } }
  __syncthreads();

  const int w = tid >> 6, lane = tid & 63;
  // GEMM1: [64,512] @ W1[512,512], wave owns 8 n16-tiles
  f32x4 acc[4][8];
  f32x4 vz = {0.f,0.f,0.f,0.f};
  #pragma unroll
  for (int a = 0; a < 4; ++a)
    #pragma unroll
    for (int n = 0; n < 8; ++n) acc[a][n] = vz;
  for (int k32 = 0; k32 < 16; ++k32){
    s16x8 av[4];
    #pragma unroll
    for (int mt = 0; mt < 4; ++mt) av[mt] = *(const s16x8*)&xf[((mt*16 + k32)*64 + lane)*8];
    #pragma unroll
    for (int nn = 0; nn < 8; ++nn){
      const int n16 = w*8 + nn;
      s16x8 bv = *(const s16x8*)&w1p[((size_t)(n16*16 + k32)*64 + lane)*8];
      #pragma unroll
      for (int mt = 0; mt < 4; ++mt)
        acc[mt][nn] = __builtin_amdgcn_mfma_f32_16x16x32_bf16(av[mt], bv, acc[mt][nn], 0,0,0);
    }
  }
  #pragma unroll
  for (int nn = 0; nn < 8; ++nn){
    int col = (w*8 + nn)*16 + (lane & 15);
    float bv = b1d[col];
    #pragma unroll
    for (int mt = 0; mt < 4; ++mt){
      #pragma unroll
      for (int rr = 0; rr < 4; ++rr){
        int row = mt*16 + ((lane >> 4) << 2) + rr;
        float v = acc[mt][nn][rr] + bv;
        v = fmaxf(v, 0.f);
        yf[((mt*16 + (col>>5))*64 + ((col>>3)&3)*16 + (row&15))*8 + (col&7)] = f2bf(v);
      } } }
  __syncthreads();

  // GEMM2: [64,512] @ W2[512,64], wave owns n16-tile w
  f32x4 acc2[4];
  #pragma unroll
  for (int mt = 0; mt < 4; ++mt) acc2[mt] = vz;
  for (int k32 = 0; k32 < 16; ++k32){
    s16x8 bv = *(const s16x8*)&w2p[((size_t)(w*16 + k32)*64 + lane)*8];
    #pragma unroll
    for (int mt = 0; mt < 4; ++mt){
      s16x8 av = *(const s16x8*)&yf[((mt*16 + k32)*64 + lane)*8];
      acc2[mt] = __builtin_amdgcn_mfma_f32_16x16x32_bf16(av, bv, acc2[mt], 0,0,0);
    } }
  const int f = w*16 + (lane & 15);
  const float bf_ = b2d[f];
  #pragma unroll
  for (int mt = 0; mt < 4; ++mt)
    #pragma unroll
    for (int rr = 0; rr < 4; ++rr){
      int row = mt*16 + ((lane >> 4) << 2) + rr;             // batch index
      out[((size_t)row*T_LEN + t)*64 + f] = tanh_f(acc2[mt][rr] + bf_);
    }
}

// ---------------------------------------------------------------------------
extern "C" void kernel_launch(void* const* d_in, const int* in_sizes, int n_in,
                              void* d_out, int out_size, void* d_ws, size_t ws_size,
                              hipStream_t stream)
{
  const float* z    = (const float*)d_in[0];
  const float* Wp   = (const float*)d_in[1];
  const float* bp   = (const float*)d_in[2];
  const float* Ws   = (const float*)d_in[3];
  const float* bs   = (const float*)d_in[4];
  const float* K0   = (const float*)d_in[5];
  const float* R0   = (const float*)d_in[6];
  const float* b0   = (const float*)d_in[7];
  const float* K1   = (const float*)d_in[8];
  const float* R1   = (const float*)d_in[9];
  const float* b1   = (const float*)d_in[10];
  const float* K2   = (const float*)d_in[11];
  const float* R2   = (const float*)d_in[12];
  const float* b2   = (const float*)d_in[13];
  const float* gam  = (const float*)d_in[14];
  const float* bet  = (const float*)d_in[15];
  const float* W1   = (const float*)d_in[16];
  const float* b1d  = (const float*)d_in[17];
  const float* W2   = (const float*)d_in[18];
  const float* b2d  = (const float*)d_in[19];
  float* out = (float*)d_out;
  (void)in_sizes; (void)n_in; (void)out_size; (void)ws_size;

  char* base = (char*)d_ws;
  size_t off = 0;
  auto carve = [&](size_t bytes)->char* {
    char* p = base + off;
    off = (off + bytes + 255) & ~(size_t)255;
    return p;
  };
  u16*   wgt0 = (u16*)  carve((size_t)64*20480*2);   // [R0;Wf0] packed
  u16*   wgt1 = (u16*)  carve((size_t)64*32768*2);   // [R1;K1]
  u16*   wgt2 = (u16*)  carve((size_t)64*36864*2);   // [R2;K2;Wf2]
  u16*   w1p  = (u16*)  carve((size_t)262144*2);
  u16*   w2p  = (u16*)  carve((size_t)32768*2);
  u16*   zp   = (u16*)  carve((size_t)2097152*2);    // z in A-frag layout
  float* Wf0  = (float*)carve((size_t)262144*4);
  float* Wf2  = (float*)carve((size_t)262144*4);
  float* gb0  = (float*)carve((size_t)2048*4);
  float* gb2  = (float*)carve((size_t)2048*4);
  u16*   hb   = (u16*)  carve((size_t)393216*2);     // 3 layers x 4 slots x 64KB
  float* hout = (float*)carve((size_t)8388608*4);    // lstm2 output [t][b][512]
  int*   flags= (int*)  carve((size_t)4096);

  k_fuse<<<dim3(8,32), dim3(256), 0, stream>>>(Wp, K0, Ws, K2, Wf0, Wf2);
  k_bias<<<dim3(16),   dim3(256), 0, stream>>>(bp, K0, b0, bs, K2, b2, gb0, gb2);
  k_zero<<<dim3(768),  dim3(256), 0, stream>>>((u32*)hb, flags);
  k_pack<<<dim3(4096), dim3(256), 0, stream>>>(R0, Wf0, R1, K1, R2, K2, Wf2, W1, W2, z,
                                               wgt0, wgt1, wgt2, w1p, w2p, zp);
  k_wave<<<dim3(192),  dim3(256), 0, stream>>>(wgt0, wgt1, wgt2, zp, hb, hout, flags,
                                               gb0, b1, gb2);
  k_ep<<<dim3(256),    dim3(256), 0, stream>>>(hout, gam, bet, w1p, w2p, b1d, b2d, out);
}

// Round 4
// 2076.335 us; speedup vs baseline: 4.8701x; 1.3223x over previous
//
#include <hip/hip_runtime.h>
#include <hip/hip_fp16.h>
#include <stdint.h>

typedef unsigned short u16;
typedef unsigned int   u32;
typedef unsigned long long u64;
typedef __attribute__((ext_vector_type(8))) short s16x8;
typedef __attribute__((ext_vector_type(8))) _Float16 h16x8;
typedef __attribute__((ext_vector_type(4))) float f32x4;

#define T_LEN 256

__device__ __forceinline__ u16 f2h(float f){ return __half_as_ushort(__float2half(f)); }
__device__ __forceinline__ h16x8 as_h(s16x8 v){ union{s16x8 s; h16x8 h;} u; u.s=v; return u.h; }
__device__ __forceinline__ float sigm(float x){ return 1.f/(1.f + __expf(-x)); }
__device__ __forceinline__ float tanh_f(float x){ return 2.f*sigm(2.f*x) - 1.f; }

// agent-coherent (LLC) 16B load as two 8B relaxed atomics: bypasses L1/L2 so
// cross-XCD h reads are fresh WITHOUT any cache maintenance.
__device__ __forceinline__ s16x8 ldh(const u16* p){
  u64 lo = __hip_atomic_load((const u64*)p,       __ATOMIC_RELAXED, __HIP_MEMORY_SCOPE_AGENT);
  u64 hi = __hip_atomic_load((const u64*)(p + 4), __ATOMIC_RELAXED, __HIP_MEMORY_SCOPE_AGENT);
  union { u64 q[2]; s16x8 v; } u;
  u.q[0] = lo; u.q[1] = hi;
  return u.v;
}

// ---------------------------------------------------------------------------
// k_fuse: Wf0 = Wp@K0  [128,2048] (K=1024); Wf2 = Ws@K2 [128,2048] (K=512)
// ---------------------------------------------------------------------------
__global__ void k_fuse(const float* __restrict__ Wp, const float* __restrict__ K0,
                       const float* __restrict__ Ws, const float* __restrict__ K2,
                       float* __restrict__ Wf0, float* __restrict__ Wf2)
{
  const int c  = blockIdx.x*256 + threadIdx.x;   // 0..2047
  const int by = blockIdx.y;                     // 0..31
  float acc[8] = {0,0,0,0,0,0,0,0};
  if (by < 16){
    const int r0 = by*8;
    for (int d = 0; d < 1024; ++d){
      float kv = K0[(size_t)d*2048 + c];
      #pragma unroll
      for (int ii = 0; ii < 8; ++ii) acc[ii] = fmaf(Wp[(size_t)(r0+ii)*1024 + d], kv, acc[ii]);
    }
    #pragma unroll
    for (int ii = 0; ii < 8; ++ii) Wf0[(size_t)(r0+ii)*2048 + c] = acc[ii];
  } else {
    const int r0 = (by-16)*8;
    for (int u = 0; u < 512; ++u){
      float kv = K2[(size_t)u*2048 + c];
      #pragma unroll
      for (int ii = 0; ii < 8; ++ii) acc[ii] = fmaf(Ws[(size_t)(r0+ii)*512 + u], kv, acc[ii]);
    }
    #pragma unroll
    for (int ii = 0; ii < 8; ++ii) Wf2[(size_t)(r0+ii)*2048 + c] = acc[ii];
  }
}

// ---------------------------------------------------------------------------
// k_bias: gb0 = bp@K0 + b0 ; gb2 = bs@K2 + b2   (each [2048])
// ---------------------------------------------------------------------------
__global__ void k_bias(const float* __restrict__ bp, const float* __restrict__ K0,
                       const float* __restrict__ b0, const float* __restrict__ bs,
                       const float* __restrict__ K2, const float* __restrict__ b2,
                       float* __restrict__ gb0, float* __restrict__ gb2)
{
  const int bx = blockIdx.x;
  if (bx < 8){
    int c = bx*256 + threadIdx.x;
    float a = b0[c];
    for (int d = 0; d < 1024; ++d) a = fmaf(bp[d], K0[(size_t)d*2048 + c], a);
    gb0[c] = a;
  } else {
    int c = (bx-8)*256 + threadIdx.x;
    float a = b2[c];
    for (int u = 0; u < 512; ++u) a = fmaf(bs[u], K2[(size_t)u*2048 + c], a);
    gb2[c] = a;
  }
}

// ---------------------------------------------------------------------------
// k_zero: zero h ring buffers (3 layers x 4 slots x 64KB), done counters = 0
// ---------------------------------------------------------------------------
__global__ void k_zero(u32* __restrict__ hbz, int* __restrict__ done)
{
  int idx = blockIdx.x*256 + threadIdx.x;       // grid 768*256 = 196608 = hb u32 count
  if (idx < 196608) hbz[idx] = 0u;
  if (blockIdx.x == 0 && threadIdx.x < 3) done[threadIdx.x*32] = 0;
}

// ---------------------------------------------------------------------------
// packing index helpers
// MFMA 16x16x32 f16 frag conventions used everywhere:
//   A: lane holds A[m=lane&15][k=(lane>>4)*8+e]  (8 contiguous f16 = 16B)
//   B: lane holds B[k=(lane>>4)*8+e][n=lane&15]
//   C/D: lane reg r holds D[row=(lane>>4)*4+r][col=lane&15]   (m89-verified,
//   dtype-independent on gfx950)
// Buffers store tiles as [tile][k32][lane][8] so a wave load is 1KB contiguous.
// ---------------------------------------------------------------------------
__device__ __forceinline__ size_t gidx(int k, int c, int K32c){
  // gate-interleaved per-WG layout: WG j owns units j*8..j*8+7, local col lc = gate*8+uu
  int gate = c >> 9, u = c & 511;
  int jj = u >> 3, uu = u & 7;
  int lc = gate*8 + uu;
  return ((size_t)(jj*2 + (lc>>4))*K32c + (k>>5))*512
         + (size_t)((((k>>3)&3)*16 + (lc&15))*8) + (size_t)(k&7);
}
__device__ __forceinline__ size_t fidx(int k, int c){
  return ((size_t)(c>>4)*16 + (k>>5))*512
         + (size_t)((((k>>3)&3)*16 + (c&15))*8) + (size_t)(k&7);
}

// ---------------------------------------------------------------------------
// k_pack: f16-pack all wavefront weights ([R0;Wf0], [R1;K1], [R2;K2;Wf2]),
// epilogue weights (W1,W2), and z into A-frag layout (zp).
// ---------------------------------------------------------------------------
__global__ void k_pack(const float* __restrict__ R0, const float* __restrict__ Wf0,
                       const float* __restrict__ R1, const float* __restrict__ K1,
                       const float* __restrict__ R2, const float* __restrict__ K2,
                       const float* __restrict__ Wf2, const float* __restrict__ W1,
                       const float* __restrict__ W2, const float* __restrict__ z,
                       u16* __restrict__ wgt0, u16* __restrict__ wgt1, u16* __restrict__ wgt2,
                       u16* __restrict__ w1p,  u16* __restrict__ w2p,  u16* __restrict__ zp)
{
  const long NT = 8159232;
  for (long i = (long)blockIdx.x*256 + threadIdx.x; i < NT; i += (long)gridDim.x*256){
    if (i < 1310720){                                   // layer0: K=640
      int k = (int)(i >> 11), c = (int)(i & 2047);
      float v = (k < 512) ? R0[(size_t)k*2048 + c] : Wf0[(size_t)(k-512)*2048 + c];
      wgt0[gidx(k, c, 20)] = f2h(v);
    } else if (i < 3407872){                            // layer1: K=1024
      long i2 = i - 1310720; int k = (int)(i2 >> 11), c = (int)(i2 & 2047);
      float v = (k < 512) ? R1[(size_t)k*2048 + c] : K1[(size_t)(k-512)*2048 + c];
      wgt1[gidx(k, c, 32)] = f2h(v);
    } else if (i < 5767168){                            // layer2: K=1152
      long i2 = i - 3407872; int k = (int)(i2 >> 11), c = (int)(i2 & 2047);
      float v = (k < 512)  ? R2[(size_t)k*2048 + c]
              : (k < 1024) ? K2[(size_t)(k-512)*2048 + c]
                           : Wf2[(size_t)(k-1024)*2048 + c];
      wgt2[gidx(k, c, 36)] = f2h(v);
    } else if (i < 6029312){                            // W1 [512,512]
      long i2 = i - 5767168; int k = (int)(i2 >> 9), c = (int)(i2 & 511);
      w1p[fidx(k, c)] = f2h(W1[(size_t)k*512 + c]);
    } else if (i < 6062080){                            // W2 [512,64]
      long i2 = i - 6029312; int k = (int)(i2 >> 6), c = (int)(i2 & 63);
      w2p[fidx(k, c)] = f2h(W2[(size_t)k*64 + c]);
    } else {                                            // z -> A-frag layout per t
      long i2 = i - 6062080;
      int bb = (int)(i2 >> 15), rem = (int)(i2 & 32767);
      int tt = rem >> 7, k = rem & 127;
      zp[(((size_t)tt*4 + (bb>>4))*4 + (k>>5))*512
         + (size_t)((((k>>3)&3)*16 + (bb&15))*8) + (size_t)(k&7)] = f2h(z[i2]);
    }
  }
}

// ---------------------------------------------------------------------------
// k_wave: persistent 3-layer LSTM wavefront. 192 blocks (layer = bid>>6,
// WG j = bid&63 owns hidden units j*8..j*8+7 = 32 gate columns).
// Per global step s, layer L computes t=s-L.
// Sync redesign (R4):
//  * h chunks published via u64 atomic_exchange (agent scope): an RMW executes
//    AT the LLC, so vmcnt completion == globally visible. Old values are
//    XOR-consumed to scratch so the exchange can't be demoted to a store.
//    (R2/R3's plain-store + "vmcnt drain" left a fabric-ordering hole: flag
//    could land before data -> R3's absmax 0.07 failure.)
//  * Per-layer monotone `done` counters (atomicAdd after the drain barrier)
//    replace 192 per-block flags; ONE thread polls <=3 words. R2/R3 had ~190
//    blocks x ~130 threads hammering 6 LLC flag lines every poll interval --
//    that contention was the 9.6us/step, not the compute.
// ---------------------------------------------------------------------------
__global__ __launch_bounds__(256, 1) void k_wave(
    const u16* __restrict__ wgt0, const u16* __restrict__ wgt1, const u16* __restrict__ wgt2,
    const u16* __restrict__ zp, u16* __restrict__ hb, float* __restrict__ hout,
    int* done, u64* __restrict__ ackdump, const float* __restrict__ gb0,
    const float* __restrict__ b1g, const float* __restrict__ gb2)
{
  __shared__ __align__(16) u16 wsm[2*36*512];      // 72KB weight slice
  __shared__ float zg[64][33];                     // padded: gate reads conflict-free
  __shared__ __align__(16) u16 hsh[64][8];         // h staging tile (1KB)
  const int tid = threadIdx.x;
  const int bid = blockIdx.x;
  const int L   = bid >> 6;
  const int j   = bid & 63;
  const int K32r = (L==0) ? 20 : ((L==1) ? 32 : 36);

  // load my weight slice into LDS (resident for all 256 steps)
  { const u16* wsrc = (L==0) ? wgt0 + (size_t)j*20480
                    : (L==1) ? wgt1 + (size_t)j*32768
                             : wgt2 + (size_t)j*36864;
    const uint4* s4 = (const uint4*)wsrc; uint4* d4 = (uint4*)wsm;
    const int n4 = K32r*128;
    for (int i = tid; i < n4; i += 256) d4[i] = s4[i]; }

  const int b    = tid & 63;        // batch row (gate stage)
  const int q    = tid >> 6;        // wave id; gate stage owns units 2q, 2q+1
  const int w    = q;               // m-tile for MFMA stage
  const int lane = tid & 63;

  float bias[2][4];
  { const float* bsrc = (L==0) ? gb0 : (L==1) ? b1g : gb2;
    #pragma unroll
    for (int ci = 0; ci < 2; ++ci){
      int ucol = j*8 + 2*q + ci;
      #pragma unroll
      for (int g = 0; g < 4; ++g) bias[ci][g] = bsrc[g*512 + ucol];
    } }
  float cst0 = 0.f, cst1 = 0.f;     // fp32 cell state, register-resident
  u64 ackacc = 0;

  // h-chunk store mapping (tid < 128): 4 chunks of 256B, one per m-tile
  const int smt   = tid >> 5;            // m-tile
  const int sbm   = (tid >> 1) & 15;     // batch-in-tile
  const int shalf = tid & 1;             // u64 half of 16B fragment
  const size_t schunk = ((size_t)(smt*16 + (j>>2))*64 + ((j&3)*16 + sbm))*8 + shalf*4;

  __syncthreads();

  for (int s = 0; s < T_LEN + 2; ++s){
    // ---- wait on per-layer done counters (single poller, tiny LLC footprint)
    if (tid == 0){
      int g = 0;
      for (;;){
        int okk = 1;
        if (L > 0)
          okk &= (__hip_atomic_load(&done[(L-1)*32], __ATOMIC_RELAXED, __HIP_MEMORY_SCOPE_AGENT) >= 64*s);
        okk &= (__hip_atomic_load(&done[L*32],     __ATOMIC_RELAXED, __HIP_MEMORY_SCOPE_AGENT) >= 64*s);
        if (L < 2)
          okk &= (__hip_atomic_load(&done[(L+1)*32], __ATOMIC_RELAXED, __HIP_MEMORY_SCOPE_AGENT) >= 64*(s-2));
        if (okk || ++g > (1<<20)) break;
        __builtin_amdgcn_s_sleep(8);
      }
    }
    __syncthreads();

    const int t = s - L;
    float hv0 = 0.f, hv1 = 0.f;
    if (t >= 0 && t < T_LEN){
      const int slp = (s + 3) & 3;  // previous slot
      f32x4 acc0 = {0.f,0.f,0.f,0.f};
      f32x4 acc1 = {0.f,0.f,0.f,0.f};
      const size_t wl8 = (size_t)w*8192 + (size_t)lane*8;
      const u16* h0p = hb + (size_t)(0*4 + slp)*32768 + wl8;
      const u16* h1p = hb + (size_t)(1*4 + slp)*32768 + wl8;
      const u16* h2p = hb + (size_t)(2*4 + slp)*32768 + wl8;
      const u16* zpt = zp + (size_t)t*8192 + (size_t)w*2048 + (size_t)lane*8;

      // ---- all A-fragments prefetched up front: one LLC latency window
      if (L == 0){
        s16x8 areg[20];
        #pragma unroll
        for (int kk = 0; kk < 16; ++kk) areg[kk] = ldh(h0p + (size_t)kk*512);
        #pragma unroll
        for (int kk = 0; kk < 4; ++kk)  areg[16+kk] = *(const s16x8*)(zpt + (size_t)kk*512);
        #pragma unroll
        for (int kk = 0; kk < 20; ++kk){
          h16x8 bv0 = as_h(*(const s16x8*)&wsm[kk*512 + lane*8]);
          h16x8 bv1 = as_h(*(const s16x8*)&wsm[(20+kk)*512 + lane*8]);
          acc0 = __builtin_amdgcn_mfma_f32_16x16x32_f16(as_h(areg[kk]), bv0, acc0, 0, 0, 0);
          acc1 = __builtin_amdgcn_mfma_f32_16x16x32_f16(as_h(areg[kk]), bv1, acc1, 0, 0, 0);
        }
      } else if (L == 1){
        s16x8 areg[32];
        #pragma unroll
        for (int kk = 0; kk < 16; ++kk) areg[kk]    = ldh(h1p + (size_t)kk*512);
        #pragma unroll
        for (int kk = 0; kk < 16; ++kk) areg[16+kk] = ldh(h0p + (size_t)kk*512);
        #pragma unroll
        for (int kk = 0; kk < 32; ++kk){
          h16x8 bv0 = as_h(*(const s16x8*)&wsm[kk*512 + lane*8]);
          h16x8 bv1 = as_h(*(const s16x8*)&wsm[(32+kk)*512 + lane*8]);
          acc0 = __builtin_amdgcn_mfma_f32_16x16x32_f16(as_h(areg[kk]), bv0, acc0, 0, 0, 0);
          acc1 = __builtin_amdgcn_mfma_f32_16x16x32_f16(as_h(areg[kk]), bv1, acc1, 0, 0, 0);
        }
      } else {
        s16x8 areg[36];
        #pragma unroll
        for (int kk = 0; kk < 16; ++kk) areg[kk]    = ldh(h2p + (size_t)kk*512);
        #pragma unroll
        for (int kk = 0; kk < 16; ++kk) areg[16+kk] = ldh(h1p + (size_t)kk*512);
        #pragma unroll
        for (int kk = 0; kk < 4; ++kk)  areg[32+kk] = *(const s16x8*)(zpt + (size_t)kk*512);
        #pragma unroll
        for (int kk = 0; kk < 36; ++kk){
          h16x8 bv0 = as_h(*(const s16x8*)&wsm[kk*512 + lane*8]);
          h16x8 bv1 = as_h(*(const s16x8*)&wsm[(36+kk)*512 + lane*8]);
          acc0 = __builtin_amdgcn_mfma_f32_16x16x32_f16(as_h(areg[kk]), bv0, acc0, 0, 0, 0);
          acc1 = __builtin_amdgcn_mfma_f32_16x16x32_f16(as_h(areg[kk]), bv1, acc1, 0, 0, 0);
        }
      }
      #pragma unroll
      for (int r = 0; r < 4; ++r){
        int row = (w << 4) + ((lane >> 4) << 2) + r;   // C/D: row=(lane>>4)*4+r
        zg[row][lane & 15]        = acc0[r];
        zg[row][16 + (lane & 15)] = acc1[r];
      }
      __syncthreads();

      // ---- gates: thread handles (b, units 2q and 2q+1); c stays fp32 in regs
      {
        int uu = 2*q;
        float zi = zg[b][uu]      + bias[0][0];
        float zf = zg[b][8 + uu]  + bias[0][1];
        float zc = zg[b][16 + uu] + bias[0][2];
        float zo = zg[b][24 + uu] + bias[0][3];
        float cc = sigm(zf)*cst0 + sigm(zi)*tanh_f(zc);
        cst0 = cc; hv0 = sigm(zo)*tanh_f(cc);
      }
      {
        int uu = 2*q + 1;
        float zi = zg[b][uu]      + bias[1][0];
        float zf = zg[b][8 + uu]  + bias[1][1];
        float zc = zg[b][16 + uu] + bias[1][2];
        float zo = zg[b][24 + uu] + bias[1][3];
        float cc = sigm(zf)*cst1 + sigm(zi)*tanh_f(zc);
        cst1 = cc; hv1 = sigm(zo)*tanh_f(cc);
      }
      // stage h in LDS, then publish as coalesced 256B chunks of u64 atomic
      // exchanges: completion == arrived at LLC (old value round-trips back).
      *(u32*)&hsh[b][2*q] = (u32)f2h(hv0) | ((u32)f2h(hv1) << 16);
      __syncthreads();
      if (tid < 128){
        u16* hdst = hb + (size_t)(L*4 + (s & 3))*32768;
        u64 v = *(const u64*)&hsh[smt*16 + sbm][shalf*4];
        u64 old = __hip_atomic_exchange((u64*)(hdst + schunk), v,
                                        __ATOMIC_RELAXED, __HIP_MEMORY_SCOPE_AGENT);
        ackacc ^= old;
      }
    }
    // ---- publish step s: barrier waits the exchange round-trips (data at
    // LLC), then one atomicAdd to the layer's monotone done counter.
    __syncthreads();
    if (tid == 0)
      __hip_atomic_fetch_add(&done[L*32], 1, __ATOMIC_RELAXED, __HIP_MEMORY_SCOPE_AGENT);
    if (L == 2 && t >= 0 && t < T_LEN){
      size_t o = ((size_t)t*64 + b)*512 + j*8 + 2*q;
      hout[o]     = hv0;   // plain cached store; flushed at kernel end for k_ep
      hout[o + 1] = hv1;
    }
  }
  if (tid < 128) ackdump[((size_t)bid << 7) + tid] = ackacc;  // consume exchanges
}

// ---------------------------------------------------------------------------
// k_ep: per-t block (256 blocks): LayerNorm -> W1+relu -> W2+tanh -> out
// ---------------------------------------------------------------------------
__global__ __launch_bounds__(256) void k_ep(
    const float* __restrict__ hout, const float* __restrict__ gam, const float* __restrict__ bet,
    const u16* __restrict__ w1p, const u16* __restrict__ w2p,
    const float* __restrict__ b1d, const float* __restrict__ b2d, float* __restrict__ out)
{
  __shared__ __align__(16) u16 xf[32768];   // LN(x) f16, frag layout [mt][k32][lane][8]
  __shared__ __align__(16) u16 yf[32768];   // relu(xW1+b) f16, frag layout
  __shared__ float redS[64][8];
  __shared__ float muS[64], rsS[64];
  const int t = blockIdx.x, tid = threadIdx.x;
  const int r = tid >> 2, qq = tid & 3;

  const float4* x4 = (const float4*)(hout + ((size_t)t*64 + r)*512 + qq*128);
  float sum = 0.f, sq = 0.f;
  #pragma unroll 8
  for (int i = 0; i < 32; ++i){
    float4 v = x4[i];
    sum += v.x + v.y + v.z + v.w;
    sq  += v.x*v.x + v.y*v.y + v.z*v.z + v.w*v.w;
  }
  redS[r][qq] = sum; redS[r][4+qq] = sq;
  __syncthreads();
  if (qq == 0){
    float s1 = redS[r][0]+redS[r][1]+redS[r][2]+redS[r][3];
    float s2 = redS[r][4]+redS[r][5]+redS[r][6]+redS[r][7];
    float m  = s1 * (1.f/512.f);
    float var = s2 * (1.f/512.f) - m*m;
    muS[r] = m; rsS[r] = rsqrtf(var + 1e-3f);
  }
  __syncthreads();
  { const float m = muS[r], rstd = rsS[r];
    const int mt = r >> 4, rl = r & 15;
    for (int i = 0; i < 32; ++i){
      float4 v = x4[i];
      int k0 = qq*128 + i*4;
      float vv[4] = {v.x, v.y, v.z, v.w};
      #pragma unroll
      for (int e = 0; e < 4; ++e){
        int k = k0 + e;
        float xn = (vv[e] - m)*rstd*gam[k] + bet[k];
        xf[((mt*16 + (k>>5))*64 + ((k>>3)&3)*16 + rl)*8 + (k&7)] = f2h(xn);
      }
    } }
  __syncthreads();

  const int w = tid >> 6, lane = tid & 63;
  // GEMM1: [64,512] @ W1[512,512], wave owns 8 n16-tiles
  f32x4 acc[4][8];
  f32x4 vz = {0.f,0.f,0.f,0.f};
  #pragma unroll
  for (int a = 0; a < 4; ++a)
    #pragma unroll
    for (int n = 0; n < 8; ++n) acc[a][n] = vz;
  for (int k32 = 0; k32 < 16; ++k32){
    h16x8 av[4];
    #pragma unroll
    for (int mt = 0; mt < 4; ++mt) av[mt] = as_h(*(const s16x8*)&xf[((mt*16 + k32)*64 + lane)*8]);
    #pragma unroll
    for (int nn = 0; nn < 8; ++nn){
      const int n16 = w*8 + nn;
      h16x8 bv = as_h(*(const s16x8*)&w1p[((size_t)(n16*16 + k32)*64 + lane)*8]);
      #pragma unroll
      for (int mt = 0; mt < 4; ++mt)
        acc[mt][nn] = __builtin_amdgcn_mfma_f32_16x16x32_f16(av[mt], bv, acc[mt][nn], 0,0,0);
    }
  }
  #pragma unroll
  for (int nn = 0; nn < 8; ++nn){
    int col = (w*8 + nn)*16 + (lane & 15);
    float bv = b1d[col];
    #pragma unroll
    for (int mt = 0; mt < 4; ++mt){
      #pragma unroll
      for (int rr = 0; rr < 4; ++rr){
        int row = mt*16 + ((lane >> 4) << 2) + rr;
        float v = acc[mt][nn][rr] + bv;
        v = fmaxf(v, 0.f);
        yf[((mt*16 + (col>>5))*64 + ((col>>3)&3)*16 + (row&15))*8 + (col&7)] = f2h(v);
      } } }
  __syncthreads();

  // GEMM2: [64,512] @ W2[512,64], wave owns n16-tile w
  f32x4 acc2[4];
  #pragma unroll
  for (int mt = 0; mt < 4; ++mt) acc2[mt] = vz;
  for (int k32 = 0; k32 < 16; ++k32){
    h16x8 bv = as_h(*(const s16x8*)&w2p[((size_t)(w*16 + k32)*64 + lane)*8]);
    #pragma unroll
    for (int mt = 0; mt < 4; ++mt){
      h16x8 av = as_h(*(const s16x8*)&yf[((mt*16 + k32)*64 + lane)*8]);
      acc2[mt] = __builtin_amdgcn_mfma_f32_16x16x32_f16(av, bv, acc2[mt], 0,0,0);
    } }
  const int f = w*16 + (lane & 15);
  const float bf_ = b2d[f];
  #pragma unroll
  for (int mt = 0; mt < 4; ++mt)
    #pragma unroll
    for (int rr = 0; rr < 4; ++rr){
      int row = mt*16 + ((lane >> 4) << 2) + rr;             // batch index
      out[((size_t)row*T_LEN + t)*64 + f] = tanh_f(acc2[mt][rr] + bf_);
    }
}

// ---------------------------------------------------------------------------
extern "C" void kernel_launch(void* const* d_in, const int* in_sizes, int n_in,
                              void* d_out, int out_size, void* d_ws, size_t ws_size,
                              hipStream_t stream)
{
  const float* z    = (const float*)d_in[0];
  const float* Wp   = (const float*)d_in[1];
  const float* bp   = (const float*)d_in[2];
  const float* Ws   = (const float*)d_in[3];
  const float* bs   = (const float*)d_in[4];
  const float* K0   = (const float*)d_in[5];
  const float* R0   = (const float*)d_in[6];
  const float* b0   = (const float*)d_in[7];
  const float* K1   = (const float*)d_in[8];
  const float* R1   = (const float*)d_in[9];
  const float* b1   = (const float*)d_in[10];
  const float* K2   = (const float*)d_in[11];
  const float* R2   = (const float*)d_in[12];
  const float* b2   = (const float*)d_in[13];
  const float* gam  = (const float*)d_in[14];
  const float* bet  = (const float*)d_in[15];
  const float* W1   = (const float*)d_in[16];
  const float* b1d  = (const float*)d_in[17];
  const float* W2   = (const float*)d_in[18];
  const float* b2d  = (const float*)d_in[19];
  float* out = (float*)d_out;
  (void)in_sizes; (void)n_in; (void)out_size; (void)ws_size;

  char* base = (char*)d_ws;
  size_t off = 0;
  auto carve = [&](size_t bytes)->char* {
    char* p = base + off;
    off = (off + bytes + 255) & ~(size_t)255;
    return p;
  };
  u16*   wgt0 = (u16*)  carve((size_t)64*20480*2);   // [R0;Wf0] packed
  u16*   wgt1 = (u16*)  carve((size_t)64*32768*2);   // [R1;K1]
  u16*   wgt2 = (u16*)  carve((size_t)64*36864*2);   // [R2;K2;Wf2]
  u16*   w1p  = (u16*)  carve((size_t)262144*2);
  u16*   w2p  = (u16*)  carve((size_t)32768*2);
  u16*   zp   = (u16*)  carve((size_t)2097152*2);    // z in A-frag layout
  float* Wf0  = (float*)carve((size_t)262144*4);
  float* Wf2  = (float*)carve((size_t)262144*4);
  float* gb0  = (float*)carve((size_t)2048*4);
  float* gb2  = (float*)carve((size_t)2048*4);
  u16*   hb   = (u16*)  carve((size_t)393216*2);     // 3 layers x 4 slots x 64KB
  float* hout = (float*)carve((size_t)8388608*4);    // lstm2 output [t][b][512]
  int*   done = (int*)  carve((size_t)512);          // 3 counters, 128B apart
  u64*   ackd = (u64*)  carve((size_t)192*128*8);    // exchange-result dump

  k_fuse<<<dim3(8,32), dim3(256), 0, stream>>>(Wp, K0, Ws, K2, Wf0, Wf2);
  k_bias<<<dim3(16),   dim3(256), 0, stream>>>(bp, K0, b0, bs, K2, b2, gb0, gb2);
  k_zero<<<dim3(768),  dim3(256), 0, stream>>>((u32*)hb, done);
  k_pack<<<dim3(4096), dim3(256), 0, stream>>>(R0, Wf0, R1, K1, R2, K2, Wf2, W1, W2, z,
                                               wgt0, wgt1, wgt2, w1p, w2p, zp);
  k_wave<<<dim3(192),  dim3(256), 0, stream>>>(wgt0, wgt1, wgt2, zp, hb, hout, done,
                                               ackd, gb0, b1, gb2);
  k_ep<<<dim3(256),    dim3(256), 0, stream>>>(hout, gam, bet, w1p, w2p, b1d, b2d, out);
}

// Round 5
// 1930.331 us; speedup vs baseline: 5.2384x; 1.0756x over previous
//
#include <hip/hip_runtime.h>
#include <hip/hip_fp16.h>
#include <stdint.h>

typedef unsigned short u16;
typedef unsigned int   u32;
typedef unsigned long long u64;
typedef __attribute__((ext_vector_type(8))) short s16x8;
typedef __attribute__((ext_vector_type(8))) _Float16 h16x8;
typedef __attribute__((ext_vector_type(4))) float f32x4;

#define T_LEN 256

__device__ __forceinline__ u16 f2h(float f){ return __half_as_ushort(__float2half(f)); }
__device__ __forceinline__ float h2f(u16 x){ union{u16 u; _Float16 h;} c; c.u = x; return (float)c.h; }
__device__ __forceinline__ h16x8 as_h(s16x8 v){ union{s16x8 s; h16x8 h;} u; u.s=v; return u.h; }
__device__ __forceinline__ float sigm(float x){ return 1.f/(1.f + __expf(-x)); }
__device__ __forceinline__ float tanh_f(float x){ return 2.f*sigm(2.f*x) - 1.f; }

// ---------------------------------------------------------------------------
// k_fuse: Wf0 = Wp@K0  [128,2048] (K=1024); Wf2 = Ws@K2 [128,2048] (K=512)
// ---------------------------------------------------------------------------
__global__ void k_fuse(const float* __restrict__ Wp, const float* __restrict__ K0,
                       const float* __restrict__ Ws, const float* __restrict__ K2,
                       float* __restrict__ Wf0, float* __restrict__ Wf2)
{
  const int c  = blockIdx.x*256 + threadIdx.x;   // 0..2047
  const int by = blockIdx.y;                     // 0..31
  float acc[8] = {0,0,0,0,0,0,0,0};
  if (by < 16){
    const int r0 = by*8;
    for (int d = 0; d < 1024; ++d){
      float kv = K0[(size_t)d*2048 + c];
      #pragma unroll
      for (int ii = 0; ii < 8; ++ii) acc[ii] = fmaf(Wp[(size_t)(r0+ii)*1024 + d], kv, acc[ii]);
    }
    #pragma unroll
    for (int ii = 0; ii < 8; ++ii) Wf0[(size_t)(r0+ii)*2048 + c] = acc[ii];
  } else {
    const int r0 = (by-16)*8;
    for (int u = 0; u < 512; ++u){
      float kv = K2[(size_t)u*2048 + c];
      #pragma unroll
      for (int ii = 0; ii < 8; ++ii) acc[ii] = fmaf(Ws[(size_t)(r0+ii)*512 + u], kv, acc[ii]);
    }
    #pragma unroll
    for (int ii = 0; ii < 8; ++ii) Wf2[(size_t)(r0+ii)*2048 + c] = acc[ii];
  }
}

// ---------------------------------------------------------------------------
// k_bias: gb0 = bp@K0 + b0 ; gb2 = bs@K2 + b2   (each [2048])
// ---------------------------------------------------------------------------
__global__ void k_bias(const float* __restrict__ bp, const float* __restrict__ K0,
                       const float* __restrict__ b0, const float* __restrict__ bs,
                       const float* __restrict__ K2, const float* __restrict__ b2,
                       float* __restrict__ gb0, float* __restrict__ gb2)
{
  const int bx = blockIdx.x;
  if (bx < 8){
    int c = bx*256 + threadIdx.x;
    float a = b0[c];
    for (int d = 0; d < 1024; ++d) a = fmaf(bp[d], K0[(size_t)d*2048 + c], a);
    gb0[c] = a;
  } else {
    int c = (bx-8)*256 + threadIdx.x;
    float a = b2[c];
    for (int u = 0; u < 512; ++u) a = fmaf(bs[u], K2[(size_t)u*2048 + c], a);
    gb2[c] = a;
  }
}

// ---------------------------------------------------------------------------
// k_zero: zero the t=-1 h slots (3 x 64KB) and flags = -1.
// Dirty lines flush at this kernel's end-of-dispatch writeback, so k_wave's
// cold plain loads see zeros.
// ---------------------------------------------------------------------------
__global__ void k_zero(u32* __restrict__ hfz, int* __restrict__ flags)
{
  int idx = blockIdx.x*256 + threadIdx.x;
  if (idx < 49152){                       // 3 layers x 16384 u32 (64KB slot)
    int L = idx >> 14, off = idx & 16383;
    hfz[(size_t)L*257*16384 + off] = 0u;
  }
  if (blockIdx.x == 0 && threadIdx.x < 192) flags[threadIdx.x] = -1;
}

// ---------------------------------------------------------------------------
// packing index helpers
// MFMA 16x16x32 f16 frag conventions used everywhere:
//   A: lane holds A[m=lane&15][k=(lane>>4)*8+e]  (8 contiguous f16 = 16B)
//   B: lane holds B[k=(lane>>4)*8+e][n=lane&15]
//   C/D: lane reg r holds D[row=(lane>>4)*4+r][col=lane&15]
// Buffers store tiles as [tile][k32][lane][8] so a wave load is 1KB contiguous.
// ---------------------------------------------------------------------------
__device__ __forceinline__ size_t gidx(int k, int c, int K32c){
  int gate = c >> 9, u = c & 511;
  int jj = u >> 3, uu = u & 7;
  int lc = gate*8 + uu;
  return ((size_t)(jj*2 + (lc>>4))*K32c + (k>>5))*512
         + (size_t)((((k>>3)&3)*16 + (lc&15))*8) + (size_t)(k&7);
}
__device__ __forceinline__ size_t fidx(int k, int c){
  return ((size_t)(c>>4)*16 + (k>>5))*512
         + (size_t)((((k>>3)&3)*16 + (c&15))*8) + (size_t)(k&7);
}

// ---------------------------------------------------------------------------
// k_pack: f16-pack all wavefront weights ([R0;Wf0], [R1;K1], [R2;K2;Wf2]),
// epilogue weights (W1,W2), and z into A-frag layout (zp).
// ---------------------------------------------------------------------------
__global__ void k_pack(const float* __restrict__ R0, const float* __restrict__ Wf0,
                       const float* __restrict__ R1, const float* __restrict__ K1,
                       const float* __restrict__ R2, const float* __restrict__ K2,
                       const float* __restrict__ Wf2, const float* __restrict__ W1,
                       const float* __restrict__ W2, const float* __restrict__ z,
                       u16* __restrict__ wgt0, u16* __restrict__ wgt1, u16* __restrict__ wgt2,
                       u16* __restrict__ w1p,  u16* __restrict__ w2p,  u16* __restrict__ zp)
{
  const long NT = 8159232;
  for (long i = (long)blockIdx.x*256 + threadIdx.x; i < NT; i += (long)gridDim.x*256){
    if (i < 1310720){                                   // layer0: K=640
      int k = (int)(i >> 11), c = (int)(i & 2047);
      float v = (k < 512) ? R0[(size_t)k*2048 + c] : Wf0[(size_t)(k-512)*2048 + c];
      wgt0[gidx(k, c, 20)] = f2h(v);
    } else if (i < 3407872){                            // layer1: K=1024
      long i2 = i - 1310720; int k = (int)(i2 >> 11), c = (int)(i2 & 2047);
      float v = (k < 512) ? R1[(size_t)k*2048 + c] : K1[(size_t)(k-512)*2048 + c];
      wgt1[gidx(k, c, 32)] = f2h(v);
    } else if (i < 5767168){                            // layer2: K=1152
      long i2 = i - 3407872; int k = (int)(i2 >> 11), c = (int)(i2 & 2047);
      float v = (k < 512)  ? R2[(size_t)k*2048 + c]
              : (k < 1024) ? K2[(size_t)(k-512)*2048 + c]
                           : Wf2[(size_t)(k-1024)*2048 + c];
      wgt2[gidx(k, c, 36)] = f2h(v);
    } else if (i < 6029312){                            // W1 [512,512]
      long i2 = i - 5767168; int k = (int)(i2 >> 9), c = (int)(i2 & 511);
      w1p[fidx(k, c)] = f2h(W1[(size_t)k*512 + c]);
    } else if (i < 6062080){                            // W2 [512,64]
      long i2 = i - 6029312; int k = (int)(i2 >> 6), c = (int)(i2 & 63);
      w2p[fidx(k, c)] = f2h(W2[(size_t)k*64 + c]);
    } else {                                            // z -> A-frag layout per t
      long i2 = i - 6062080;
      int bb = (int)(i2 >> 15), rem = (int)(i2 & 32767);
      int tt = rem >> 7, k = rem & 127;
      zp[(((size_t)tt*4 + (bb>>4))*4 + (k>>5))*512
         + (size_t)((((k>>3)&3)*16 + (bb&15))*8) + (size_t)(k&7)] = f2h(z[i2]);
    }
  }
}

// ---------------------------------------------------------------------------
// k_wave: persistent 3-layer LSTM wavefront. 192 blocks (layer = bid>>6,
// WG j = bid&63 owns hidden units j*8..j*8+7 = 32 gate columns).
// R5 data-distribution redesign:
//  * h lives in FRESH 64KB slots per (layer, t) -- no ring reuse. Consumers
//    read via PLAIN cached dwordx4 loads: slots are cold in every L1/L2 until
//    first post-flag touch (producers publish via sc1 xchg which never
//    allocates into L2; earlier kernels' dirty lines flush at their dispatch
//    end). XCD L2 now broadcasts h to the ~24 co-located WGs instead of each
//    doing 8B agent-atomic LLC ops (R4: ~2.6M LLC ops/step = the 7.4us wall).
//  * No ring => no producer-credit wait; L0 runs ahead elastically.
//  * Flags: per-WG monotone step counters (64/layer, dense -> a wave poll
//    coalesces to 4 line fetches). Wave 0 polls, s_sleep(2), then barrier.
//  * Publish ordering unchanged (R4-proven): xchg (completes at LLC) ->
//    barrier -> flag store.
// ---------------------------------------------------------------------------
__global__ __launch_bounds__(256, 1) void k_wave(
    const u16* __restrict__ wgt0, const u16* __restrict__ wgt1, const u16* __restrict__ wgt2,
    const u16* __restrict__ zp, u16* __restrict__ hf, int* flags,
    u64* __restrict__ ackdump, const float* __restrict__ gb0,
    const float* __restrict__ b1g, const float* __restrict__ gb2)
{
  __shared__ __align__(16) u16 wsm[2*36*512];      // 72KB weight slice
  __shared__ float zg[64][33];                     // padded: gate reads conflict-free
  __shared__ __align__(16) u16 hsh[64][8];         // h staging tile (1KB)
  const int tid = threadIdx.x;
  const int bid = blockIdx.x;
  const int L   = bid >> 6;
  const int j   = bid & 63;
  const int K32r = (L==0) ? 20 : ((L==1) ? 32 : 36);

  // load my weight slice into LDS (resident for all 256 steps)
  { const u16* wsrc = (L==0) ? wgt0 + (size_t)j*20480
                    : (L==1) ? wgt1 + (size_t)j*32768
                             : wgt2 + (size_t)j*36864;
    const uint4* s4 = (const uint4*)wsrc; uint4* d4 = (uint4*)wsm;
    const int n4 = K32r*128;
    for (int i = tid; i < n4; i += 256) d4[i] = s4[i]; }

  const int b    = tid & 63;        // batch row (gate stage)
  const int q    = tid >> 6;        // wave id; gate stage owns units 2q, 2q+1
  const int w    = q;               // m-tile for MFMA stage
  const int lane = tid & 63;

  float bias[2][4];
  { const float* bsrc = (L==0) ? gb0 : (L==1) ? b1g : gb2;
    #pragma unroll
    for (int ci = 0; ci < 2; ++ci){
      int ucol = j*8 + 2*q + ci;
      #pragma unroll
      for (int g = 0; g < 4; ++g) bias[ci][g] = bsrc[g*512 + ucol];
    } }
  float cst0 = 0.f, cst1 = 0.f;     // fp32 cell state, register-resident
  u64 ackacc = 0;

  // h-chunk store mapping (tid < 128): 4 chunks of 256B, one per m-tile
  const int smt   = tid >> 5;            // m-tile
  const int sbm   = (tid >> 1) & 15;     // batch-in-tile
  const int shalf = tid & 1;             // u64 half of 16B fragment
  const size_t schunk = ((size_t)(smt*16 + (j>>2))*64 + ((j&3)*16 + sbm))*8 + shalf*4;

  __syncthreads();

  for (int s = 0; s < T_LEN + 2; ++s){
    // ---- wave 0 polls per-WG flags: self layer and layer below >= s-1
    if (q == 0){
      const int need = s - 1;
      int g = 0;
      for (;;){
        int okk = (__hip_atomic_load(&flags[L*64 + lane], __ATOMIC_RELAXED,
                                     __HIP_MEMORY_SCOPE_AGENT) >= need);
        if (L > 0)
          okk &= (__hip_atomic_load(&flags[(L-1)*64 + lane], __ATOMIC_RELAXED,
                                    __HIP_MEMORY_SCOPE_AGENT) >= need);
        if (__all(okk) || ++g > (1<<20)) break;
        __builtin_amdgcn_s_sleep(2);
      }
    }
    __syncthreads();

    const int t = s - L;
    if (t >= 0 && t < T_LEN){
      f32x4 acc0 = {0.f,0.f,0.f,0.f};
      f32x4 acc1 = {0.f,0.f,0.f,0.f};
      const size_t wl8 = (size_t)w*8192 + (size_t)lane*8;
      // fresh slot addressing: slot(L,tt) at (L*257 + tt + 1)*32768
      const u16* hself = hf + ((size_t)(L*257 + t))*32768 + wl8;            // h_L(t-1)
      const u16* hblw  = (L > 0) ? hf + ((size_t)((L-1)*257 + t + 1))*32768 + wl8 : nullptr;
      const u16* zpt   = zp + (size_t)t*8192 + (size_t)w*2048 + (size_t)lane*8;

      // ---- plain cached A-fragment loads (L2 broadcast), all in one window
      if (L == 0){
        s16x8 areg[20];
        #pragma unroll
        for (int kk = 0; kk < 16; ++kk) areg[kk]    = *(const s16x8*)(hself + (size_t)kk*512);
        #pragma unroll
        for (int kk = 0; kk < 4; ++kk)  areg[16+kk] = *(const s16x8*)(zpt   + (size_t)kk*512);
        #pragma unroll
        for (int kk = 0; kk < 20; ++kk){
          h16x8 bv0 = as_h(*(const s16x8*)&wsm[kk*512 + lane*8]);
          h16x8 bv1 = as_h(*(const s16x8*)&wsm[(20+kk)*512 + lane*8]);
          acc0 = __builtin_amdgcn_mfma_f32_16x16x32_f16(as_h(areg[kk]), bv0, acc0, 0, 0, 0);
          acc1 = __builtin_amdgcn_mfma_f32_16x16x32_f16(as_h(areg[kk]), bv1, acc1, 0, 0, 0);
        }
      } else if (L == 1){
        s16x8 areg[32];
        #pragma unroll
        for (int kk = 0; kk < 16; ++kk) areg[kk]    = *(const s16x8*)(hself + (size_t)kk*512);
        #pragma unroll
        for (int kk = 0; kk < 16; ++kk) areg[16+kk] = *(const s16x8*)(hblw  + (size_t)kk*512);
        #pragma unroll
        for (int kk = 0; kk < 32; ++kk){
          h16x8 bv0 = as_h(*(const s16x8*)&wsm[kk*512 + lane*8]);
          h16x8 bv1 = as_h(*(const s16x8*)&wsm[(32+kk)*512 + lane*8]);
          acc0 = __builtin_amdgcn_mfma_f32_16x16x32_f16(as_h(areg[kk]), bv0, acc0, 0, 0, 0);
          acc1 = __builtin_amdgcn_mfma_f32_16x16x32_f16(as_h(areg[kk]), bv1, acc1, 0, 0, 0);
        }
      } else {
        s16x8 areg[36];
        #pragma unroll
        for (int kk = 0; kk < 16; ++kk) areg[kk]    = *(const s16x8*)(hself + (size_t)kk*512);
        #pragma unroll
        for (int kk = 0; kk < 16; ++kk) areg[16+kk] = *(const s16x8*)(hblw  + (size_t)kk*512);
        #pragma unroll
        for (int kk = 0; kk < 4; ++kk)  areg[32+kk] = *(const s16x8*)(zpt   + (size_t)kk*512);
        #pragma unroll
        for (int kk = 0; kk < 36; ++kk){
          h16x8 bv0 = as_h(*(const s16x8*)&wsm[kk*512 + lane*8]);
          h16x8 bv1 = as_h(*(const s16x8*)&wsm[(36+kk)*512 + lane*8]);
          acc0 = __builtin_amdgcn_mfma_f32_16x16x32_f16(as_h(areg[kk]), bv0, acc0, 0, 0, 0);
          acc1 = __builtin_amdgcn_mfma_f32_16x16x32_f16(as_h(areg[kk]), bv1, acc1, 0, 0, 0);
        }
      }
      #pragma unroll
      for (int r = 0; r < 4; ++r){
        int row = (w << 4) + ((lane >> 4) << 2) + r;   // C/D: row=(lane>>4)*4+r
        zg[row][lane & 15]        = acc0[r];
        zg[row][16 + (lane & 15)] = acc1[r];
      }
      __syncthreads();

      // ---- gates: thread handles (b, units 2q and 2q+1); c stays fp32 in regs
      float hv0, hv1;
      {
        int uu = 2*q;
        float zi = zg[b][uu]      + bias[0][0];
        float zf = zg[b][8 + uu]  + bias[0][1];
        float zc = zg[b][16 + uu] + bias[0][2];
        float zo = zg[b][24 + uu] + bias[0][3];
        float cc = sigm(zf)*cst0 + sigm(zi)*tanh_f(zc);
        cst0 = cc; hv0 = sigm(zo)*tanh_f(cc);
      }
      {
        int uu = 2*q + 1;
        float zi = zg[b][uu]      + bias[1][0];
        float zf = zg[b][8 + uu]  + bias[1][1];
        float zc = zg[b][16 + uu] + bias[1][2];
        float zo = zg[b][24 + uu] + bias[1][3];
        float cc = sigm(zf)*cst1 + sigm(zi)*tanh_f(zc);
        cst1 = cc; hv1 = sigm(zo)*tanh_f(cc);
      }
      // stage h in LDS, then publish as coalesced 256B chunks of u64 atomic
      // exchanges: completion == arrived at LLC (old value round-trips back).
      *(u32*)&hsh[b][2*q] = (u32)f2h(hv0) | ((u32)f2h(hv1) << 16);
      __syncthreads();
      if (tid < 128){
        u16* hdst = hf + ((size_t)(L*257 + t + 1))*32768;
        u64 v = *(const u64*)&hsh[smt*16 + sbm][shalf*4];
        u64 old = __hip_atomic_exchange((u64*)(hdst + schunk), v,
                                        __ATOMIC_RELAXED, __HIP_MEMORY_SCOPE_AGENT);
        ackacc ^= old;
      }
    }
    // ---- publish step s: barrier waits the exchange round-trips (data at
    // LLC), then one relaxed flag store per WG.
    __syncthreads();
    if (tid == 0)
      __hip_atomic_store(&flags[L*64 + j], s, __ATOMIC_RELAXED, __HIP_MEMORY_SCOPE_AGENT);
  }
  if (tid < 128) ackdump[((size_t)bid << 7) + tid] = ackacc;  // consume exchanges
}

// ---------------------------------------------------------------------------
// k_ep: per-t block (256 blocks): stage h2(t) slot (fp16 frag layout) ->
// LayerNorm -> W1+relu -> W2+tanh -> out. Reads k_wave's published slots
// directly (kernel-boundary coherence); hout buffer eliminated.
// ---------------------------------------------------------------------------
__global__ __launch_bounds__(256) void k_ep(
    const u16* __restrict__ hf, const float* __restrict__ gam, const float* __restrict__ bet,
    const u16* __restrict__ w1p, const u16* __restrict__ w2p,
    const float* __restrict__ b1d, const float* __restrict__ b2d, float* __restrict__ out)
{
  __shared__ __align__(16) u16 xs[32768];   // staged h2 slot -> LN(x), frag layout
  __shared__ __align__(16) u16 yf[32768];   // relu(xW1+b) f16, frag layout
  __shared__ float redS[64][8];
  __shared__ float muS[64], rsS[64];
  const int t = blockIdx.x, tid = threadIdx.x;

  // stage the 64KB h2(t) slot into LDS
  { const uint4* src = (const uint4*)(hf + ((size_t)(2*257 + t + 1))*32768);
    uint4* dst = (uint4*)xs;
    #pragma unroll
    for (int i = 0; i < 16; ++i) dst[tid + 256*i] = src[tid + 256*i]; }
  __syncthreads();

  // LN stats: thread (r, qq) sums k in [qq*128, qq*128+128) for row r
  const int r = tid >> 2, qq = tid & 3;
  const int mt = r >> 4, ml = r & 15;
  float sum = 0.f, sq = 0.f;
  #pragma unroll
  for (int k32 = qq*4; k32 < qq*4 + 4; ++k32)
    #pragma unroll
    for (int kq = 0; kq < 4; ++kq){
      s16x8 v = *(const s16x8*)&xs[(((mt*16 + k32)*64) + kq*16 + ml)*8];
      #pragma unroll
      for (int e = 0; e < 8; ++e){
        float x = h2f(((const u16*)&v)[e]);
        sum += x; sq += x*x;
      }
    }
  redS[r][qq] = sum; redS[r][4+qq] = sq;
  __syncthreads();
  if (qq == 0){
    float s1 = redS[r][0]+redS[r][1]+redS[r][2]+redS[r][3];
    float s2 = redS[r][4]+redS[r][5]+redS[r][6]+redS[r][7];
    float m  = s1 * (1.f/512.f);
    float var = s2 * (1.f/512.f) - m*m;
    muS[r] = m; rsS[r] = rsqrtf(var + 1e-3f);
  }
  __syncthreads();
  // normalize in place
  { const float m = muS[r], rstd = rsS[r];
    #pragma unroll
    for (int k32 = qq*4; k32 < qq*4 + 4; ++k32)
      #pragma unroll
      for (int kq = 0; kq < 4; ++kq){
        u16* pp = &xs[(((mt*16 + k32)*64) + kq*16 + ml)*8];
        s16x8 v = *(const s16x8*)pp;
        #pragma unroll
        for (int e = 0; e < 8; ++e){
          int k = k32*32 + kq*8 + e;
          float xn = (h2f(((const u16*)&v)[e]) - m)*rstd*gam[k] + bet[k];
          pp[e] = f2h(xn);
        }
      } }
  __syncthreads();

  const int w = tid >> 6, lane = tid & 63;
  // GEMM1: [64,512] @ W1[512,512], wave owns 8 n16-tiles
  f32x4 acc[4][8];
  f32x4 vz = {0.f,0.f,0.f,0.f};
  #pragma unroll
  for (int a = 0; a < 4; ++a)
    #pragma unroll
    for (int n = 0; n < 8; ++n) acc[a][n] = vz;
  for (int k32 = 0; k32 < 16; ++k32){
    h16x8 av[4];
    #pragma unroll
    for (int mt2 = 0; mt2 < 4; ++mt2) av[mt2] = as_h(*(const s16x8*)&xs[((mt2*16 + k32)*64 + lane)*8]);
    #pragma unroll
    for (int nn = 0; nn < 8; ++nn){
      const int n16 = w*8 + nn;
      h16x8 bv = as_h(*(const s16x8*)&w1p[((size_t)(n16*16 + k32)*64 + lane)*8]);
      #pragma unroll
      for (int mt2 = 0; mt2 < 4; ++mt2)
        acc[mt2][nn] = __builtin_amdgcn_mfma_f32_16x16x32_f16(av[mt2], bv, acc[mt2][nn], 0,0,0);
    }
  }
  #pragma unroll
  for (int nn = 0; nn < 8; ++nn){
    int col = (w*8 + nn)*16 + (lane & 15);
    float bv = b1d[col];
    #pragma unroll
    for (int mt2 = 0; mt2 < 4; ++mt2){
      #pragma unroll
      for (int rr = 0; rr < 4; ++rr){
        int row = mt2*16 + ((lane >> 4) << 2) + rr;
        float v = acc[mt2][nn][rr] + bv;
        v = fmaxf(v, 0.f);
        yf[((mt2*16 + (col>>5))*64 + ((col>>3)&3)*16 + (row&15))*8 + (col&7)] = f2h(v);
      } } }
  __syncthreads();

  // GEMM2: [64,512] @ W2[512,64], wave owns n16-tile w
  f32x4 acc2[4];
  #pragma unroll
  for (int mt2 = 0; mt2 < 4; ++mt2) acc2[mt2] = vz;
  for (int k32 = 0; k32 < 16; ++k32){
    h16x8 bv = as_h(*(const s16x8*)&w2p[((size_t)(w*16 + k32)*64 + lane)*8]);
    #pragma unroll
    for (int mt2 = 0; mt2 < 4; ++mt2){
      h16x8 av = as_h(*(const s16x8*)&yf[((mt2*16 + k32)*64 + lane)*8]);
      acc2[mt2] = __builtin_amdgcn_mfma_f32_16x16x32_f16(av, bv, acc2[mt2], 0,0,0);
    } }
  const int f = w*16 + (lane & 15);
  const float bf_ = b2d[f];
  #pragma unroll
  for (int mt2 = 0; mt2 < 4; ++mt2)
    #pragma unroll
    for (int rr = 0; rr < 4; ++rr){
      int row = mt2*16 + ((lane >> 4) << 2) + rr;             // batch index
      out[((size_t)row*T_LEN + t)*64 + f] = tanh_f(acc2[mt2][rr] + bf_);
    }
}

// ---------------------------------------------------------------------------
extern "C" void kernel_launch(void* const* d_in, const int* in_sizes, int n_in,
                              void* d_out, int out_size, void* d_ws, size_t ws_size,
                              hipStream_t stream)
{
  const float* z    = (const float*)d_in[0];
  const float* Wp   = (const float*)d_in[1];
  const float* bp   = (const float*)d_in[2];
  const float* Ws   = (const float*)d_in[3];
  const float* bs   = (const float*)d_in[4];
  const float* K0   = (const float*)d_in[5];
  const float* R0   = (const float*)d_in[6];
  const float* b0   = (const float*)d_in[7];
  const float* K1   = (const float*)d_in[8];
  const float* R1   = (const float*)d_in[9];
  const float* b1   = (const float*)d_in[10];
  const float* K2   = (const float*)d_in[11];
  const float* R2   = (const float*)d_in[12];
  const float* b2   = (const float*)d_in[13];
  const float* gam  = (const float*)d_in[14];
  const float* bet  = (const float*)d_in[15];
  const float* W1   = (const float*)d_in[16];
  const float* b1d  = (const float*)d_in[17];
  const float* W2   = (const float*)d_in[18];
  const float* b2d  = (const float*)d_in[19];
  float* out = (float*)d_out;
  (void)in_sizes; (void)n_in; (void)out_size; (void)ws_size;

  char* base = (char*)d_ws;
  size_t off = 0;
  auto carve = [&](size_t bytes)->char* {
    char* p = base + off;
    off = (off + bytes + 255) & ~(size_t)255;
    return p;
  };
  u16*   wgt0 = (u16*)  carve((size_t)64*20480*2);   // [R0;Wf0] packed
  u16*   wgt1 = (u16*)  carve((size_t)64*32768*2);   // [R1;K1]
  u16*   wgt2 = (u16*)  carve((size_t)64*36864*2);   // [R2;K2;Wf2]
  u16*   w1p  = (u16*)  carve((size_t)262144*2);
  u16*   w2p  = (u16*)  carve((size_t)32768*2);
  u16*   zp   = (u16*)  carve((size_t)2097152*2);    // z in A-frag layout
  float* Wf0  = (float*)carve((size_t)262144*4);
  float* Wf2  = (float*)carve((size_t)262144*4);
  float* gb0  = (float*)carve((size_t)2048*4);
  float* gb2  = (float*)carve((size_t)2048*4);
  u16*   hf   = (u16*)  carve((size_t)3*257*32768*2);// fresh h slots, 48MB
  int*   flags= (int*)  carve((size_t)1024);         // 192 per-WG step flags
  u64*   ackd = (u64*)  carve((size_t)192*128*8);    // exchange-result dump

  k_fuse<<<dim3(8,32), dim3(256), 0, stream>>>(Wp, K0, Ws, K2, Wf0, Wf2);
  k_bias<<<dim3(16),   dim3(256), 0, stream>>>(bp, K0, b0, bs, K2, b2, gb0, gb2);
  k_zero<<<dim3(768),  dim3(256), 0, stream>>>((u32*)hf, flags);
  k_pack<<<dim3(4096), dim3(256), 0, stream>>>(R0, Wf0, R1, K1, R2, K2, Wf2, W1, W2, z,
                                               wgt0, wgt1, wgt2, w1p, w2p, zp);
  k_wave<<<dim3(192),  dim3(256), 0, stream>>>(wgt0, wgt1, wgt2, zp, hf, flags,
                                               ackd, gb0, b1, gb2);
  k_ep<<<dim3(256),    dim3(256), 0, stream>>>(hf, gam, bet, w1p, w2p, b1d, b2d, out);
}